// Round 14
// baseline (346.840 us; speedup 1.0000x reference)
//
#include <hip/hip_runtime.h>
#include <math.h>

constexpr int Fdim = 256;
constexpr int Hdim = 256;
constexpr int Kc   = 16;

constexpr int RSTRIDE = 32;
constexpr int NRED    = 34;   // 0..15 nl, 16..31 cluster_sizes, 32 con, 33 trace
constexpr int BCAP    = 5120; // bucket capacity (mean 4096, 16 sigma slack)

typedef __attribute__((ext_vector_type(8))) short s8v;   // 8 bf16 (4 VGPRs)
typedef __attribute__((ext_vector_type(4))) float f4v;   // 4 fp32 acc
typedef __attribute__((ext_vector_type(2))) float f2v;   // packed f32 pair
typedef __attribute__((ext_vector_type(4))) unsigned u4v;

__device__ __forceinline__ float selu1(float x){
    const float scale = 1.0507009873554805f;
    const float alpha = 1.6732632423543772f;
    return scale * (x > 0.f ? x : alpha * expm1f(x));
}

__device__ __forceinline__ ushort f2bf(float x){
    union { float f; unsigned u; } c; c.f = x;
    unsigned r = c.u + 0x7fffu + ((c.u >> 16) & 1u);   // RNE
    return (ushort)(r >> 16);
}

__device__ __forceinline__ float bflo(unsigned v){
    union { unsigned u; float f; } c; c.u = v << 16; return c.f;
}
__device__ __forceinline__ float bfhi(unsigned v){
    union { unsigned u; float f; } c; c.u = v & 0xffff0000u; return c.f;
}

// fp8 e4m3 encode via HW converter (RNE)
__device__ __forceinline__ unsigned char f2fp8(float x){
    int v = __builtin_amdgcn_cvt_pk_fp8_f32(x, x, 0, false);
    return (unsigned char)(v & 0xff);
}

// ---------------- CSR build phase A: LDS-staged binning ----------
__global__ __launch_bounds__(256) void bin_kernel(
        const int* __restrict__ src, const int* __restrict__ dst,
        const float* __restrict__ w,
        int* __restrict__ bcnt,
        int* __restrict__ bsrc, uint2* __restrict__ bdw, int E, int nbuck){
    __shared__ int hist[256];
    __shared__ int base[256];
    __shared__ int cur[256];
    int t = threadIdx.x;
    int chunk = (E + gridDim.x - 1) / gridDim.x;
    int lo = blockIdx.x * chunk;
    int hi = min(lo + chunk, E);
    hist[t] = 0;
    __syncthreads();
    for (int i = lo + t; i < hi; i += 256)
        atomicAdd(&hist[src[i] >> 8], 1);
    __syncthreads();
    if (t < nbuck && hist[t] > 0)
        base[t] = atomicAdd(&bcnt[t * 32], hist[t]);
    cur[t] = 0;
    __syncthreads();
    for (int i = lo + t; i < hi; i += 256){
        int s = src[i], d = dst[i];
        float wv = w[i];
        int b = s >> 8;
        int p = base[b] + atomicAdd(&cur[b], 1);
        if (p < BCAP){
            bsrc[(size_t)b * BCAP + p] = s;
            bdw[(size_t)b * BCAP + p]  = make_uint2((unsigned)d, __float_as_uint(wv));
        }
    }
}

// ---------------- bucket-base scan (single block) + roff[n] ----------------
__global__ __launch_bounds__(256) void bbase_kernel(const int* __restrict__ bcnt,
        int* __restrict__ bbase, int* __restrict__ roff, int nbuck, int n){
    __shared__ int s[256];
    int t = threadIdx.x;
    int v = (t < nbuck) ? min(bcnt[t * 32], BCAP) : 0;
    s[t] = v;
    __syncthreads();
    for (int off = 1; off < 256; off <<= 1){
        int x = (t >= off) ? s[t - off] : 0;
        __syncthreads();
        s[t] += x;
        __syncthreads();
    }
    if (t < nbuck) bbase[t] = s[t] - v;   // exclusive
    if (t == 255) roff[n] = s[255];       // total = E
}

// ---------------- per-bucket: src hist + scan -> roff slice, then scatter ----------
__global__ __launch_bounds__(256) void csr_build_kernel(
        const int* __restrict__ bcnt, const int* __restrict__ bbase,
        const int* __restrict__ bsrc, const uint2* __restrict__ bdw,
        int* __restrict__ roff, uint2* __restrict__ csr, int n){
    __shared__ int hist[256];
    __shared__ int loc[256];
    __shared__ int cur[256];
    int b = blockIdx.x, t = threadIdx.x;
    int cnt  = min(bcnt[b * 32], BCAP);
    int base = bbase[b];
    hist[t] = 0;
    __syncthreads();
    for (int i = t; i < cnt; i += 256)
        atomicAdd(&hist[bsrc[(size_t)b * BCAP + i] & 255], 1);
    __syncthreads();
    int v = hist[t];
    loc[t] = v;
    __syncthreads();
    for (int off = 1; off < 256; off <<= 1){
        int x = (t >= off) ? loc[t - off] : 0;
        __syncthreads();
        loc[t] += x;
        __syncthreads();
    }
    int gi = b * 256 + t;
    if (gi < n) roff[gi] = base + loc[t] - v;
    cur[t] = 0;
    __syncthreads();
    for (int i = t; i < cnt; i += 256){
        int s   = bsrc[(size_t)b * BCAP + i];
        int idx = s & 255;
        int p = base + (loc[idx] - hist[idx]) + atomicAdd(&cur[idx], 1);
        csr[p] = bdw[(size_t)b * BCAP + i];
    }
}

// ---------------- W1 transpose-cast: Wt[n][k] = bf16(W1[k][n]) ----------------
__global__ void castw_kernel(const float* __restrict__ W, ushort* __restrict__ Wt){
    __shared__ float t[16][17];
    int tx = threadIdx.x, ty = threadIdx.y;
    int k  = blockIdx.y * 16 + ty;
    int nn = blockIdx.x * 16 + tx;
    t[ty][tx] = W[k * 256 + nn];
    __syncthreads();
    int n2 = blockIdx.x * 16 + ty;
    int k2 = blockIdx.y * 16 + tx;
    Wt[n2 * 256 + k2] = f2bf(t[tx][ty]);
}

// ---------------- Ws/Wt transpose-cast ----------------
__global__ void castwk_kernel(const float* __restrict__ Ws, const float* __restrict__ Wt,
                              ushort* __restrict__ WsT, ushort* __restrict__ WtT){
    int h = threadIdx.x;   // 0..255
    #pragma unroll
    for (int c = 0; c < 16; ++c){
        WsT[c * 256 + h] = f2bf(Ws[h * 16 + c]);
        WtT[c * 256 + h] = f2bf(Wt[h * 16 + c]);
    }
}

// ---------------- MFMA bf16 GEMM: 2 K-phases, 32 KB LDS, 16 waves/CU ----------
// grid = (2 col-halves, ceil(M/128), 2 branches); 256 thr.
__global__ __launch_bounds__(256, 4) void gemm_xw_kernel(
        const float* __restrict__ A0, const float* __restrict__ A1,
        const ushort* __restrict__ Bt,
        unsigned char* __restrict__ C8, int M){
    __shared__ ushort blds[16384];   // 32 KB: 128 cols x 128 k (swizzled)
    int tid = threadIdx.x;
    int n0  = blockIdx.x * 128;
    int bm  = blockIdx.y * 128;
    const float* A = blockIdx.z ? A1 : A0;
    int halfoff = blockIdx.z * 256;

    int w = tid >> 6, l = tid & 63;
    int lr = l & 15, lk = l >> 4;

    int r0 = bm + w * 32 + lr;
    int r1 = r0 + 16;
    int rc0 = min(r0, M - 1), rc1 = min(r1, M - 1);

    f4v acc[2][8];
    #pragma unroll
    for (int m = 0; m < 2; ++m)
        #pragma unroll
        for (int t = 0; t < 8; ++t)
            acc[m][t] = (f4v){0.f, 0.f, 0.f, 0.f};

    for (int kp = 0; kp < 2; ++kp){
        // ---- stage B: 128 cols x 128 k = 2048 chunks of 16B ----
        #pragma unroll
        for (int j = 0; j < 8; ++j){
            int c  = j * 256 + tid;
            int nl = c >> 4, kc = c & 15;     // col, 16B-chunk within 256B row
            uint4 v = *reinterpret_cast<const uint4*>(
                Bt + (((size_t)(n0 + nl)) << 8) + kp * 128 + (kc << 3));
            unsigned boff = (unsigned)(((nl << 8) + (kc << 4)) ^ ((nl & 7) << 4));
            *reinterpret_cast<uint4*>(reinterpret_cast<char*>(blds) + boff) = v;
        }

        // ---- A loads for this k-phase (overlap with staging before barrier) ----
        const float* a0 = A + (size_t)rc0 * 256 + kp * 128 + lk * 8;
        const float* a1 = A + (size_t)rc1 * 256 + kp * 128 + lk * 8;
        s8v af0[4], af1[4];
        #pragma unroll
        for (int ks = 0; ks < 4; ++ks){
            float4 x0 = *reinterpret_cast<const float4*>(a0 + ks * 32);
            float4 x1 = *reinterpret_cast<const float4*>(a0 + ks * 32 + 4);
            af0[ks][0] = (short)f2bf(x0.x); af0[ks][1] = (short)f2bf(x0.y);
            af0[ks][2] = (short)f2bf(x0.z); af0[ks][3] = (short)f2bf(x0.w);
            af0[ks][4] = (short)f2bf(x1.x); af0[ks][5] = (short)f2bf(x1.y);
            af0[ks][6] = (short)f2bf(x1.z); af0[ks][7] = (short)f2bf(x1.w);
            float4 y0 = *reinterpret_cast<const float4*>(a1 + ks * 32);
            float4 y1 = *reinterpret_cast<const float4*>(a1 + ks * 32 + 4);
            af1[ks][0] = (short)f2bf(y0.x); af1[ks][1] = (short)f2bf(y0.y);
            af1[ks][2] = (short)f2bf(y0.z); af1[ks][3] = (short)f2bf(y0.w);
            af1[ks][4] = (short)f2bf(y1.x); af1[ks][5] = (short)f2bf(y1.y);
            af1[ks][6] = (short)f2bf(y1.z); af1[ks][7] = (short)f2bf(y1.w);
        }
        __syncthreads();

        #pragma unroll
        for (int ks = 0; ks < 4; ++ks){
            #pragma unroll
            for (int t = 0; t < 8; ++t){
                int nl = t * 16 + lr;
                unsigned boff = (unsigned)(((nl << 8) + ((ks * 4 + lk) << 4)) ^ ((nl & 7) << 4));
                s8v bf = *reinterpret_cast<const s8v*>(reinterpret_cast<const char*>(blds) + boff);
                acc[0][t] = __builtin_amdgcn_mfma_f32_16x16x32_bf16(af0[ks], bf, acc[0][t], 0, 0, 0);
                acc[1][t] = __builtin_amdgcn_mfma_f32_16x16x32_bf16(af1[ks], bf, acc[1][t], 0, 0, 0);
            }
        }
        if (kp == 0) __syncthreads();   // drain reads before restage
    }

    // fp8 store: byte addr = row*512 + halfoff + col
    #pragma unroll
    for (int m = 0; m < 2; ++m){
        #pragma unroll
        for (int t = 0; t < 8; ++t){
            int col = n0 + t * 16 + lr;
            #pragma unroll
            for (int j = 0; j < 4; ++j){
                int row = bm + w * 32 + m * 16 + lk * 4 + j;
                if (row < M) C8[(size_t)row * 512 + halfoff + col] = f2fp8(acc[m][t][j]);
            }
        }
    }
}

// ---------------- fused SPMM over H=256 (student+teacher), fp8 table, + bias + selu ----
// NT csr loads + NT output stores (keep fp8 table L2-resident); packed f32 math.
__global__ __launch_bounds__(256) void spmm_h2_kernel(
        const unsigned char* __restrict__ XWp,
        const int* __restrict__ roff, const uint2* __restrict__ csr,
        const float* __restrict__ b1,
        ushort* __restrict__ Gs, ushort* __restrict__ Gt, int n){
    int wid = threadIdx.x >> 6, lane = threadIdx.x & 63;
    int r = blockIdx.x * 4 + wid;
    if (r >= n) return;
    int half = lane >> 5;          // 0 = student, 1 = teacher
    int hl   = lane & 31;          // col group: cols hl*8 .. hl*8+7
    const unsigned char* base = XWp + lane * 8;
    const unsigned long long* csr8 = reinterpret_cast<const unsigned long long*>(csr);
    int e0 = roff[r], e1 = roff[r + 1];
    f2v acc2[4] = {(f2v){0.f,0.f}, (f2v){0.f,0.f}, (f2v){0.f,0.f}, (f2v){0.f,0.f}};

    #define ACCUM8(V, W) do{                                          \
        f2v w2_ = (f2v){(W), (W)};                                    \
        f2v fa_ = __builtin_amdgcn_cvt_pk_f32_fp8((V).x, false);      \
        f2v fb_ = __builtin_amdgcn_cvt_pk_f32_fp8((V).x, true);       \
        f2v fc_ = __builtin_amdgcn_cvt_pk_f32_fp8((V).y, false);      \
        f2v fd_ = __builtin_amdgcn_cvt_pk_f32_fp8((V).y, true);       \
        acc2[0] += w2_ * fa_; acc2[1] += w2_ * fb_;                   \
        acc2[2] += w2_ * fc_; acc2[3] += w2_ * fd_;                   \
    }while(0)

    int e = e0;
    for (; e + 7 < e1; e += 8){
        unsigned long long q0 = __builtin_nontemporal_load(csr8 + e);
        unsigned long long q1 = __builtin_nontemporal_load(csr8 + e + 1);
        unsigned long long q2 = __builtin_nontemporal_load(csr8 + e + 2);
        unsigned long long q3 = __builtin_nontemporal_load(csr8 + e + 3);
        unsigned long long q4 = __builtin_nontemporal_load(csr8 + e + 4);
        unsigned long long q5 = __builtin_nontemporal_load(csr8 + e + 5);
        unsigned long long q6 = __builtin_nontemporal_load(csr8 + e + 6);
        unsigned long long q7 = __builtin_nontemporal_load(csr8 + e + 7);
        uint2 v0 = *reinterpret_cast<const uint2*>(base + ((size_t)(unsigned)q0 << 9));
        uint2 v1 = *reinterpret_cast<const uint2*>(base + ((size_t)(unsigned)q1 << 9));
        uint2 v2 = *reinterpret_cast<const uint2*>(base + ((size_t)(unsigned)q2 << 9));
        uint2 v3 = *reinterpret_cast<const uint2*>(base + ((size_t)(unsigned)q3 << 9));
        uint2 v4 = *reinterpret_cast<const uint2*>(base + ((size_t)(unsigned)q4 << 9));
        uint2 v5 = *reinterpret_cast<const uint2*>(base + ((size_t)(unsigned)q5 << 9));
        uint2 v6 = *reinterpret_cast<const uint2*>(base + ((size_t)(unsigned)q6 << 9));
        uint2 v7 = *reinterpret_cast<const uint2*>(base + ((size_t)(unsigned)q7 << 9));
        ACCUM8(v0, __uint_as_float((unsigned)(q0 >> 32)));
        ACCUM8(v1, __uint_as_float((unsigned)(q1 >> 32)));
        ACCUM8(v2, __uint_as_float((unsigned)(q2 >> 32)));
        ACCUM8(v3, __uint_as_float((unsigned)(q3 >> 32)));
        ACCUM8(v4, __uint_as_float((unsigned)(q4 >> 32)));
        ACCUM8(v5, __uint_as_float((unsigned)(q5 >> 32)));
        ACCUM8(v6, __uint_as_float((unsigned)(q6 >> 32)));
        ACCUM8(v7, __uint_as_float((unsigned)(q7 >> 32)));
    }
    for (; e < e1; ++e){
        unsigned long long q = __builtin_nontemporal_load(csr8 + e);
        uint2 v = *reinterpret_cast<const uint2*>(base + ((size_t)(unsigned)q << 9));
        ACCUM8(v, __uint_as_float((unsigned)(q >> 32)));
    }
    #undef ACCUM8

    const float* bp = b1 + hl * 8;
    float4 bb0 = *reinterpret_cast<const float4*>(bp);
    float4 bb1 = *reinterpret_cast<const float4*>(bp + 4);
    float bv[8] = {bb0.x, bb0.y, bb0.z, bb0.w, bb1.x, bb1.y, bb1.z, bb1.w};
    ushort o[8];
    #pragma unroll
    for (int i = 0; i < 4; ++i){
        o[2*i]   = f2bf(selu1(acc2[i][0] + bv[2*i]));
        o[2*i+1] = f2bf(selu1(acc2[i][1] + bv[2*i+1]));
    }
    u4v ov = *reinterpret_cast<const u4v*>(o);
    ushort* gout = (half ? Gt : Gs) + (size_t)r * Hdim + hl * 8;
    __builtin_nontemporal_store(ov, reinterpret_cast<u4v*>(gout));
}

// ---------------- fused MFMA: GS = pack(Gs@Ws, Gt@Wt) bf16   [N,256]x[256,16] ----------
__global__ __launch_bounds__(256) void gemm_k2_kernel(
        const ushort* __restrict__ Gs, const ushort* __restrict__ Gt,
        const ushort* __restrict__ WsT, const ushort* __restrict__ WtT,
        unsigned* __restrict__ GSp, int n){
    int wv = blockIdx.x * 4 + (threadIdx.x >> 6);
    int l  = threadIdx.x & 63;
    int lr = l & 15, lk = l >> 4;
    int nw = (n + 15) >> 4;
    if (wv >= nw) return;
    int r0 = wv * 16;

    s8v bs_[8], bt_[8];
    #pragma unroll
    for (int ks = 0; ks < 8; ++ks){
        bs_[ks] = *reinterpret_cast<const s8v*>(WsT + lr * 256 + ks * 32 + lk * 8);
        bt_[ks] = *reinterpret_cast<const s8v*>(WtT + lr * 256 + ks * 32 + lk * 8);
    }

    f4v accs = (f4v){0.f,0.f,0.f,0.f}, acct = (f4v){0.f,0.f,0.f,0.f};
    int row = min(r0 + lr, n - 1);
    const ushort* gsrow = Gs + (size_t)row * 256 + lk * 8;
    const ushort* gtrow = Gt + (size_t)row * 256 + lk * 8;
    #pragma unroll
    for (int ks = 0; ks < 8; ++ks){
        s8v a_s = *reinterpret_cast<const s8v*>(gsrow + ks * 32);
        s8v a_t = *reinterpret_cast<const s8v*>(gtrow + ks * 32);
        accs = __builtin_amdgcn_mfma_f32_16x16x32_bf16(a_s, bs_[ks], accs, 0, 0, 0);
        acct = __builtin_amdgcn_mfma_f32_16x16x32_bf16(a_t, bt_[ks], acct, 0, 0, 0);
    }
    #pragma unroll
    for (int j = 0; j < 4; ++j){
        int rr = r0 + lk * 4 + j;
        if (rr < n){
            unsigned pv = (unsigned)f2bf(accs[j]) | ((unsigned)f2bf(acct[j]) << 16);
            GSp[(size_t)rr * 16 + lr] = pv;
        }
    }
}

// ---------------- fused: SPMM-K + softmax (both branches) + cluster/con stats --------
__global__ __launch_bounds__(256) void spmm_k2_kernel(
        const unsigned* __restrict__ GSp,
        const int* __restrict__ roff, const uint2* __restrict__ csr,
        const float* __restrict__ bsv, const float* __restrict__ btv,
        float* __restrict__ asg, float* __restrict__ red, int n){
    int tid  = threadIdx.x;
    int wid  = tid >> 6, lane = tid & 63;
    int slot = lane >> 4, j = lane & 15;
    const unsigned long long* csr8 = reinterpret_cast<const unsigned long long*>(csr);
    float bs_ = bsv[j], bt_ = btv[j];
    float cs_l = 0.f, con_l = 0.f;

    int rstride = gridDim.x * 4;
    for (int r = blockIdx.x * 4 + wid; r < n; r += rstride){
        int e0 = roff[r], e1 = roff[r + 1];
        float as_ = 0.f, at_ = 0.f;
        for (int e = e0 + slot; e < e1; e += 4){
            unsigned long long q = __builtin_nontemporal_load(csr8 + e);
            float w = __uint_as_float((unsigned)(q >> 32));
            unsigned v = GSp[(size_t)(unsigned)q * 16 + j];
            as_ = fmaf(w, bflo(v), as_);
            at_ = fmaf(w, bfhi(v), at_);
        }
        as_ += __shfl_xor(as_, 16); as_ += __shfl_xor(as_, 32);
        at_ += __shfl_xor(at_, 16); at_ += __shfl_xor(at_, 32);
        float xs = selu1(as_ + bs_);
        float xt = selu1(at_ + bt_);
        float ms = xs, mt = xt;
        #pragma unroll
        for (int off = 8; off >= 1; off >>= 1){
            ms = fmaxf(ms, __shfl_xor(ms, off));
            mt = fmaxf(mt, __shfl_xor(mt, off));
        }
        float es = expf(xs - ms), et = expf(xt - mt);
        float ss = es, st = et;
        #pragma unroll
        for (int off = 8; off >= 1; off >>= 1){
            ss += __shfl_xor(ss, off);
            st += __shfl_xor(st, off);
        }
        float a = es / ss, b = et / st;
        if (slot == 0) asg[(size_t)r * 16 + j] = a;
        cs_l += a;
        float dot = a * b, na = a * a, nb = b * b;
        #pragma unroll
        for (int off = 8; off >= 1; off >>= 1){
            dot += __shfl_xor(dot, off);
            na  += __shfl_xor(na, off);
            nb  += __shfl_xor(nb, off);
        }
        if (j == 0){
            na = fmaxf(sqrtf(na), 1e-12f);
            nb = fmaxf(sqrtf(nb), 1e-12f);
            con_l += 2.f - 2.f * dot / (na * nb);
        }
    }

    // slots hold exact duplicates -> combine then scale by 1/4
    cs_l  += __shfl_xor(cs_l, 16);  cs_l  += __shfl_xor(cs_l, 32);  cs_l  *= 0.25f;
    con_l += __shfl_xor(con_l, 16); con_l += __shfl_xor(con_l, 32); con_l *= 0.25f;

    __shared__ float part[4][17];
    if (lane < 16) part[wid][lane] = cs_l;
    if (lane == 0) part[wid][16]   = con_l;
    __syncthreads();
    if (tid < 16){
        float s = part[0][tid] + part[1][tid] + part[2][tid] + part[3][tid];
        atomicAdd(&red[(16 + tid) * RSTRIDE], s);
    } else if (tid == 16){
        float s = part[0][16] + part[1][16] + part[2][16] + part[3][16];
        atomicAdd(&red[32 * RSTRIDE], s);
    }
}

// ---------------- per-edge: trace + nl[k] = sum_e S[dst_e][k] ----------------
__global__ __launch_bounds__(256) void edge_trace_kernel(const int* __restrict__ src,
        const int* __restrict__ dst, const float* __restrict__ as_,
        float* __restrict__ red, int E){
    int tid    = blockIdx.x * blockDim.x + threadIdx.x;
    int stride = gridDim.x * blockDim.x;
    float dot = 0.f;
    float nl[16] = {};
    for (int i = tid; i < E; i += stride){
        const float4* pa = reinterpret_cast<const float4*>(as_ + (size_t)src[i] * 16);
        const float4* pb = reinterpret_cast<const float4*>(as_ + (size_t)dst[i] * 16);
        #pragma unroll
        for (int q = 0; q < 4; ++q){
            float4 va = pa[q]; float4 vb = pb[q];
            dot = fmaf(va.x, vb.x, dot); dot = fmaf(va.y, vb.y, dot);
            dot = fmaf(va.z, vb.z, dot); dot = fmaf(va.w, vb.w, dot);
            nl[q*4+0] += vb.x; nl[q*4+1] += vb.y;
            nl[q*4+2] += vb.z; nl[q*4+3] += vb.w;
        }
    }
    #pragma unroll
    for (int off = 1; off < 64; off <<= 1){
        dot += __shfl_xor(dot, off);
        #pragma unroll
        for (int k = 0; k < 16; ++k) nl[k] += __shfl_xor(nl[k], off);
    }
    __shared__ float part[4][17];
    int wid = threadIdx.x >> 6, lane = threadIdx.x & 63;
    if (lane == 0){
        #pragma unroll
        for (int k = 0; k < 16; ++k) part[wid][k] = nl[k];
        part[wid][16] = dot;
    }
    __syncthreads();
    int t = threadIdx.x;
    if (t < 16){
        float s = part[0][t] + part[1][t] + part[2][t] + part[3][t];
        atomicAdd(&red[t * RSTRIDE], s);
    } else if (t == 16){
        float s = part[0][16] + part[1][16] + part[2][16] + part[3][16];
        atomicAdd(&red[33 * RSTRIDE], s);
    }
}

// ---------------- finalize ----------------
__global__ void finalize_kernel(const float* __restrict__ red, float* __restrict__ out,
                                int n, int E){
    float trace = red[33 * RSTRIDE];
    float nl2 = 0.f, cs2 = 0.f;
    #pragma unroll
    for (int k = 0; k < 16; ++k){
        nl2 = fmaf(red[k * RSTRIDE],        red[k * RSTRIDE],        nl2);
        cs2 = fmaf(red[(16 + k) * RSTRIDE], red[(16 + k) * RSTRIDE], cs2);
    }
    float twoE = 2.f * (float)E;
    float spectral = -(trace - nl2 / twoE) / twoE;
    float cluster  = sqrtf(cs2) / (float)n * 4.f - 1.f;
    float con      = red[32 * RSTRIDE] / (float)n;
    out[0] = spectral + cluster + con;
}

extern "C" void kernel_launch(void* const* d_in, const int* in_sizes, int n_in,
                              void* d_out, int out_size, void* d_ws, size_t ws_size,
                              hipStream_t stream){
    const int*   esrc = (const int*)d_in[0];
    const int*   edst = (const int*)d_in[1];
    const float* ew   = (const float*)d_in[2];
    const float* feat = (const float*)d_in[3];
    const float* faug = (const float*)d_in[4];
    const float* W1   = (const float*)d_in[5];
    const float* b1   = (const float*)d_in[6];
    const float* Wsm  = (const float*)d_in[7];
    const float* bsv  = (const float*)d_in[8];
    const float* Wtm  = (const float*)d_in[9];
    const float* btv  = (const float*)d_in[10];
    int E = in_sizes[0];
    int N = in_sizes[3] / Fdim;

    char* ws = (char*)d_ws;
    size_t off = 0;
    auto alloc = [&](size_t bytes) -> char* {
        char* p = ws + off;
        off = (off + bytes + 255) & ~(size_t)255;
        return p;
    };
    int nbuck = (N + 255) >> 8;
    unsigned char* XWp = (unsigned char*)alloc((size_t)N * 512);  // fp8 [N][512B]
    ushort*   Gs    = (ushort*)alloc((size_t)N * Hdim * 2);
    ushort*   Gt    = (ushort*)alloc((size_t)N * Hdim * 2);
    unsigned* GSp   = (unsigned*)alloc((size_t)N * Kc * 4);
    float*    ASG_S = (float*)alloc((size_t)N * Kc * 4);
    ushort*   WT    = (ushort*)alloc((size_t)256 * 256 * 2);
    ushort*   WsT   = (ushort*)alloc((size_t)16 * 256 * 2);
    ushort*   WtT   = (ushort*)alloc((size_t)16 * 256 * 2);
    int*      ROFF  = (int*)alloc((size_t)(N + 1) * 4);
    int*      BBASE = (int*)alloc((size_t)(nbuck + 1) * 4);
    int*      BCNT  = (int*)alloc((size_t)nbuck * 32 * 4);
    int*      BSRC  = (int*)alloc((size_t)nbuck * BCAP * 4);
    uint2*    BDW   = (uint2*)alloc((size_t)nbuck * BCAP * 8);
    uint2*    CSR8  = (uint2*)alloc((size_t)E * 8);
    float*    RED   = (float*)alloc((size_t)NRED * RSTRIDE * 4);

    hipMemsetAsync(BCNT, 0, (size_t)nbuck * 32 * 4, stream);
    hipMemsetAsync(RED, 0, (size_t)NRED * RSTRIDE * 4, stream);

    castw_kernel<<<dim3(16, 16), dim3(16, 16), 0, stream>>>(W1, WT);
    castwk_kernel<<<1, 256, 0, stream>>>(Wsm, Wtm, WsT, WtT);
    bin_kernel<<<256, 256, 0, stream>>>(esrc, edst, ew, BCNT, BSRC, BDW, E, nbuck);
    bbase_kernel<<<1, 256, 0, stream>>>(BCNT, BBASE, ROFF, nbuck, N);
    csr_build_kernel<<<nbuck, 256, 0, stream>>>(BCNT, BBASE, BSRC, BDW, ROFF, CSR8, N);

    dim3 gg(2, (N + 127) / 128, 2);
    gemm_xw_kernel<<<gg, 256, 0, stream>>>(feat, faug, WT, XWp, N);

    spmm_h2_kernel<<<(N + 3) / 4, 256, 0, stream>>>(XWp, ROFF, CSR8, b1, Gs, Gt, N);

    int nw = (N + 15) / 16;
    gemm_k2_kernel<<<(nw + 3) / 4, 256, 0, stream>>>(Gs, Gt, WsT, WtT, GSp, N);

    spmm_k2_kernel<<<2048, 256, 0, stream>>>(GSp, ROFF, CSR8, bsv, btv,
                                             ASG_S, RED, N);

    edge_trace_kernel<<<256, 256, 0, stream>>>(esrc, edst, ASG_S, RED, E);
    finalize_kernel<<<1, 1, 0, stream>>>(RED, (float*)d_out, N, E);
}

// Round 15
// 291.220 us; speedup vs baseline: 1.1910x; 1.1910x over previous
//
#include <hip/hip_runtime.h>
#include <math.h>

constexpr int Fdim = 256;
constexpr int Hdim = 256;
constexpr int Kc   = 16;

constexpr int RSTRIDE = 32;
constexpr int NRED    = 34;   // 0..15 nl, 16..31 cluster_sizes, 32 con, 33 trace
constexpr int BCAP    = 5120; // bucket capacity (mean 4096, 16 sigma slack)

typedef __attribute__((ext_vector_type(8))) short s8v;   // 8 bf16 (4 VGPRs)
typedef __attribute__((ext_vector_type(4))) float f4v;   // 4 fp32 acc

__device__ __forceinline__ float selu1(float x){
    const float scale = 1.0507009873554805f;
    const float alpha = 1.6732632423543772f;
    return scale * (x > 0.f ? x : alpha * expm1f(x));
}

__device__ __forceinline__ ushort f2bf(float x){
    union { float f; unsigned u; } c; c.f = x;
    unsigned r = c.u + 0x7fffu + ((c.u >> 16) & 1u);   // RNE
    return (ushort)(r >> 16);
}

__device__ __forceinline__ float bflo(unsigned v){
    union { unsigned u; float f; } c; c.u = v << 16; return c.f;
}
__device__ __forceinline__ float bfhi(unsigned v){
    union { unsigned u; float f; } c; c.u = v & 0xffff0000u; return c.f;
}

// fp8 e4m3 encode via HW converter (RNE)
__device__ __forceinline__ unsigned char f2fp8(float x){
    int v = __builtin_amdgcn_cvt_pk_fp8_f32(x, x, 0, false);
    return (unsigned char)(v & 0xff);
}

// ---------------- CSR build phase A: LDS-staged binning ----------
__global__ __launch_bounds__(256) void bin_kernel(
        const int* __restrict__ src, const int* __restrict__ dst,
        const float* __restrict__ w,
        int* __restrict__ bcnt,
        int* __restrict__ bsrc, uint2* __restrict__ bdw, int E, int nbuck){
    __shared__ int hist[256];
    __shared__ int base[256];
    __shared__ int cur[256];
    int t = threadIdx.x;
    int chunk = (E + gridDim.x - 1) / gridDim.x;
    int lo = blockIdx.x * chunk;
    int hi = min(lo + chunk, E);
    hist[t] = 0;
    __syncthreads();
    for (int i = lo + t; i < hi; i += 256)
        atomicAdd(&hist[src[i] >> 8], 1);
    __syncthreads();
    if (t < nbuck && hist[t] > 0)
        base[t] = atomicAdd(&bcnt[t * 32], hist[t]);
    cur[t] = 0;
    __syncthreads();
    for (int i = lo + t; i < hi; i += 256){
        int s = src[i], d = dst[i];
        float wv = w[i];
        int b = s >> 8;
        int p = base[b] + atomicAdd(&cur[b], 1);
        if (p < BCAP){
            bsrc[(size_t)b * BCAP + p] = s;
            bdw[(size_t)b * BCAP + p]  = make_uint2((unsigned)d, __float_as_uint(wv));
        }
    }
}

// ---------------- bucket-base scan (single block) + roff[n] ----------------
__global__ __launch_bounds__(256) void bbase_kernel(const int* __restrict__ bcnt,
        int* __restrict__ bbase, int* __restrict__ roff, int nbuck, int n){
    __shared__ int s[256];
    int t = threadIdx.x;
    int v = (t < nbuck) ? min(bcnt[t * 32], BCAP) : 0;
    s[t] = v;
    __syncthreads();
    for (int off = 1; off < 256; off <<= 1){
        int x = (t >= off) ? s[t - off] : 0;
        __syncthreads();
        s[t] += x;
        __syncthreads();
    }
    if (t < nbuck) bbase[t] = s[t] - v;   // exclusive
    if (t == 255) roff[n] = s[255];       // total = E
}

// ---------------- per-bucket: src hist + scan -> roff slice, then scatter ----------
__global__ __launch_bounds__(256) void csr_build_kernel(
        const int* __restrict__ bcnt, const int* __restrict__ bbase,
        const int* __restrict__ bsrc, const uint2* __restrict__ bdw,
        int* __restrict__ roff, uint2* __restrict__ csr, int n){
    __shared__ int hist[256];
    __shared__ int loc[256];
    __shared__ int cur[256];
    int b = blockIdx.x, t = threadIdx.x;
    int cnt  = min(bcnt[b * 32], BCAP);
    int base = bbase[b];
    hist[t] = 0;
    __syncthreads();
    for (int i = t; i < cnt; i += 256)
        atomicAdd(&hist[bsrc[(size_t)b * BCAP + i] & 255], 1);
    __syncthreads();
    int v = hist[t];
    loc[t] = v;
    __syncthreads();
    for (int off = 1; off < 256; off <<= 1){
        int x = (t >= off) ? loc[t - off] : 0;
        __syncthreads();
        loc[t] += x;
        __syncthreads();
    }
    int gi = b * 256 + t;
    if (gi < n) roff[gi] = base + loc[t] - v;
    cur[t] = 0;
    __syncthreads();
    for (int i = t; i < cnt; i += 256){
        int s   = bsrc[(size_t)b * BCAP + i];
        int idx = s & 255;
        int p = base + (loc[idx] - hist[idx]) + atomicAdd(&cur[idx], 1);
        csr[p] = bdw[(size_t)b * BCAP + i];
    }
}

// ---------------- W1 transpose-cast: Wt[n][k] = bf16(W1[k][n]) ----------------
__global__ void castw_kernel(const float* __restrict__ W, ushort* __restrict__ Wt){
    __shared__ float t[16][17];
    int tx = threadIdx.x, ty = threadIdx.y;
    int k  = blockIdx.y * 16 + ty;
    int nn = blockIdx.x * 16 + tx;
    t[ty][tx] = W[k * 256 + nn];
    __syncthreads();
    int n2 = blockIdx.x * 16 + ty;
    int k2 = blockIdx.y * 16 + tx;
    Wt[n2 * 256 + k2] = f2bf(t[tx][ty]);
}

// ---------------- Ws/Wt transpose-cast ----------------
__global__ void castwk_kernel(const float* __restrict__ Ws, const float* __restrict__ Wt,
                              ushort* __restrict__ WsT, ushort* __restrict__ WtT){
    int h = threadIdx.x;   // 0..255
    #pragma unroll
    for (int c = 0; c < 16; ++c){
        WsT[c * 256 + h] = f2bf(Ws[h * 16 + c]);
        WtT[c * 256 + h] = f2bf(Wt[h * 16 + c]);
    }
}

// ---------------- MFMA bf16 GEMM: NO LDS — B read straight from L2 ----------
// grid = (2 col-halves, ceil(M/128), 2 branches); 256 thr; 0 LDS; no barriers.
// B is 128 KB total -> L2-resident; each B-fragment load hits 16 full 64B lines.
__global__ __launch_bounds__(256, 3) void gemm_xw_kernel(
        const float* __restrict__ A0, const float* __restrict__ A1,
        const ushort* __restrict__ Bt,
        unsigned char* __restrict__ C8, int M){
    int tid = threadIdx.x;
    int n0  = blockIdx.x * 128;
    int bm  = blockIdx.y * 128;
    const float* A = blockIdx.z ? A1 : A0;
    int halfoff = blockIdx.z * 256;

    int w = tid >> 6, l = tid & 63;
    int lr = l & 15, lk = l >> 4;

    f4v acc[2][8];
    #pragma unroll
    for (int m = 0; m < 2; ++m)
        #pragma unroll
        for (int t = 0; t < 8; ++t)
            acc[m][t] = (f4v){0.f, 0.f, 0.f, 0.f};

    int r0 = bm + w * 32 + lr;
    int r1 = r0 + 16;
    int rc0 = min(r0, M - 1), rc1 = min(r1, M - 1);
    const float* a0 = A + (size_t)rc0 * 256 + lk * 8;
    const float* a1 = A + (size_t)rc1 * 256 + lk * 8;
    // B fragment base for this lane: row (n0 + t*16 + lr), k-offset lk*8
    const ushort* bb = Bt + (((size_t)(n0 + lr)) << 8) + lk * 8;

    for (int ks = 0; ks < 8; ++ks){
        s8v af0, af1;
        {
            float4 f0 = *reinterpret_cast<const float4*>(a0 + ks * 32);
            float4 f1 = *reinterpret_cast<const float4*>(a0 + ks * 32 + 4);
            af0[0] = (short)f2bf(f0.x); af0[1] = (short)f2bf(f0.y);
            af0[2] = (short)f2bf(f0.z); af0[3] = (short)f2bf(f0.w);
            af0[4] = (short)f2bf(f1.x); af0[5] = (short)f2bf(f1.y);
            af0[6] = (short)f2bf(f1.z); af0[7] = (short)f2bf(f1.w);
        }
        {
            float4 f0 = *reinterpret_cast<const float4*>(a1 + ks * 32);
            float4 f1 = *reinterpret_cast<const float4*>(a1 + ks * 32 + 4);
            af1[0] = (short)f2bf(f0.x); af1[1] = (short)f2bf(f0.y);
            af1[2] = (short)f2bf(f0.z); af1[3] = (short)f2bf(f0.w);
            af1[4] = (short)f2bf(f1.x); af1[5] = (short)f2bf(f1.y);
            af1[6] = (short)f2bf(f1.z); af1[7] = (short)f2bf(f1.w);
        }
        // 8 independent B loads from L2
        s8v bf[8];
        #pragma unroll
        for (int t = 0; t < 8; ++t)
            bf[t] = *reinterpret_cast<const s8v*>(bb + ((size_t)t * 16 << 8) + ks * 32);
        #pragma unroll
        for (int t = 0; t < 8; ++t){
            acc[0][t] = __builtin_amdgcn_mfma_f32_16x16x32_bf16(af0, bf[t], acc[0][t], 0, 0, 0);
            acc[1][t] = __builtin_amdgcn_mfma_f32_16x16x32_bf16(af1, bf[t], acc[1][t], 0, 0, 0);
        }
    }

    // fp8 store: byte addr = row*512 + halfoff + col
    #pragma unroll
    for (int m = 0; m < 2; ++m){
        #pragma unroll
        for (int t = 0; t < 8; ++t){
            int col = n0 + t * 16 + lr;
            #pragma unroll
            for (int j = 0; j < 4; ++j){
                int row = bm + w * 32 + m * 16 + lk * 4 + j;
                if (row < M) C8[(size_t)row * 512 + halfoff + col] = f2fp8(acc[m][t][j]);
            }
        }
    }
}

// ---------------- fused SPMM over H=256 (student+teacher), fp8 table, + bias + selu ----
__global__ __launch_bounds__(256) void spmm_h2_kernel(
        const unsigned char* __restrict__ XWp,
        const int* __restrict__ roff, const uint2* __restrict__ csr,
        const float* __restrict__ b1,
        ushort* __restrict__ Gs, ushort* __restrict__ Gt, int n){
    int wid = threadIdx.x >> 6, lane = threadIdx.x & 63;
    int r = blockIdx.x * 4 + wid;
    if (r >= n) return;
    int half = lane >> 5;          // 0 = student, 1 = teacher
    int hl   = lane & 31;          // col group: cols hl*8 .. hl*8+7
    const unsigned char* base = XWp + lane * 8;
    int e0 = roff[r], e1 = roff[r + 1];
    float acc[8] = {};

    #define ACCUM8(V, W) do{                                                      \
        auto fa_ = __builtin_amdgcn_cvt_pk_f32_fp8((V).x, false);                 \
        acc[0] = fmaf((W), fa_[0], acc[0]); acc[1] = fmaf((W), fa_[1], acc[1]);   \
        auto fb_ = __builtin_amdgcn_cvt_pk_f32_fp8((V).x, true);                  \
        acc[2] = fmaf((W), fb_[0], acc[2]); acc[3] = fmaf((W), fb_[1], acc[3]);   \
        auto fc_ = __builtin_amdgcn_cvt_pk_f32_fp8((V).y, false);                 \
        acc[4] = fmaf((W), fc_[0], acc[4]); acc[5] = fmaf((W), fc_[1], acc[5]);   \
        auto fd_ = __builtin_amdgcn_cvt_pk_f32_fp8((V).y, true);                  \
        acc[6] = fmaf((W), fd_[0], acc[6]); acc[7] = fmaf((W), fd_[1], acc[7]);   \
    }while(0)

    int e = e0;
    for (; e + 7 < e1; e += 8){
        uint2 c0 = csr[e],     c1 = csr[e + 1];
        uint2 c2 = csr[e + 2], c3 = csr[e + 3];
        uint2 c4 = csr[e + 4], c5 = csr[e + 5];
        uint2 c6 = csr[e + 6], c7 = csr[e + 7];
        uint2 v0 = *reinterpret_cast<const uint2*>(base + ((size_t)c0.x << 9));
        uint2 v1 = *reinterpret_cast<const uint2*>(base + ((size_t)c1.x << 9));
        uint2 v2 = *reinterpret_cast<const uint2*>(base + ((size_t)c2.x << 9));
        uint2 v3 = *reinterpret_cast<const uint2*>(base + ((size_t)c3.x << 9));
        uint2 v4 = *reinterpret_cast<const uint2*>(base + ((size_t)c4.x << 9));
        uint2 v5 = *reinterpret_cast<const uint2*>(base + ((size_t)c5.x << 9));
        uint2 v6 = *reinterpret_cast<const uint2*>(base + ((size_t)c6.x << 9));
        uint2 v7 = *reinterpret_cast<const uint2*>(base + ((size_t)c7.x << 9));
        ACCUM8(v0, __uint_as_float(c0.y)); ACCUM8(v1, __uint_as_float(c1.y));
        ACCUM8(v2, __uint_as_float(c2.y)); ACCUM8(v3, __uint_as_float(c3.y));
        ACCUM8(v4, __uint_as_float(c4.y)); ACCUM8(v5, __uint_as_float(c5.y));
        ACCUM8(v6, __uint_as_float(c6.y)); ACCUM8(v7, __uint_as_float(c7.y));
    }
    for (; e + 3 < e1; e += 4){
        uint2 c0 = csr[e],     c1 = csr[e + 1];
        uint2 c2 = csr[e + 2], c3 = csr[e + 3];
        uint2 v0 = *reinterpret_cast<const uint2*>(base + ((size_t)c0.x << 9));
        uint2 v1 = *reinterpret_cast<const uint2*>(base + ((size_t)c1.x << 9));
        uint2 v2 = *reinterpret_cast<const uint2*>(base + ((size_t)c2.x << 9));
        uint2 v3 = *reinterpret_cast<const uint2*>(base + ((size_t)c3.x << 9));
        ACCUM8(v0, __uint_as_float(c0.y)); ACCUM8(v1, __uint_as_float(c1.y));
        ACCUM8(v2, __uint_as_float(c2.y)); ACCUM8(v3, __uint_as_float(c3.y));
    }
    for (; e < e1; ++e){
        uint2 c = csr[e];
        uint2 v = *reinterpret_cast<const uint2*>(base + ((size_t)c.x << 9));
        ACCUM8(v, __uint_as_float(c.y));
    }
    #undef ACCUM8

    const float* bp = b1 + hl * 8;
    float4 bb0 = *reinterpret_cast<const float4*>(bp);
    float4 bb1 = *reinterpret_cast<const float4*>(bp + 4);
    float bv[8] = {bb0.x, bb0.y, bb0.z, bb0.w, bb1.x, bb1.y, bb1.z, bb1.w};
    ushort o[8];
    #pragma unroll
    for (int q = 0; q < 8; ++q) o[q] = f2bf(selu1(acc[q] + bv[q]));
    uint4 ov = *reinterpret_cast<const uint4*>(o);
    ushort* gout = (half ? Gt : Gs) + (size_t)r * Hdim + hl * 8;
    *reinterpret_cast<uint4*>(gout) = ov;
}

// ---------------- fused MFMA: GS = pack(Gs@Ws, Gt@Wt) bf16   [N,256]x[256,16] ----------
__global__ __launch_bounds__(256) void gemm_k2_kernel(
        const ushort* __restrict__ Gs, const ushort* __restrict__ Gt,
        const ushort* __restrict__ WsT, const ushort* __restrict__ WtT,
        unsigned* __restrict__ GSp, int n){
    int wv = blockIdx.x * 4 + (threadIdx.x >> 6);
    int l  = threadIdx.x & 63;
    int lr = l & 15, lk = l >> 4;
    int nw = (n + 15) >> 4;
    if (wv >= nw) return;
    int r0 = wv * 16;

    s8v bs_[8], bt_[8];
    #pragma unroll
    for (int ks = 0; ks < 8; ++ks){
        bs_[ks] = *reinterpret_cast<const s8v*>(WsT + lr * 256 + ks * 32 + lk * 8);
        bt_[ks] = *reinterpret_cast<const s8v*>(WtT + lr * 256 + ks * 32 + lk * 8);
    }

    f4v accs = (f4v){0.f,0.f,0.f,0.f}, acct = (f4v){0.f,0.f,0.f,0.f};
    int row = min(r0 + lr, n - 1);
    const ushort* gsrow = Gs + (size_t)row * 256 + lk * 8;
    const ushort* gtrow = Gt + (size_t)row * 256 + lk * 8;
    #pragma unroll
    for (int ks = 0; ks < 8; ++ks){
        s8v a_s = *reinterpret_cast<const s8v*>(gsrow + ks * 32);
        s8v a_t = *reinterpret_cast<const s8v*>(gtrow + ks * 32);
        accs = __builtin_amdgcn_mfma_f32_16x16x32_bf16(a_s, bs_[ks], accs, 0, 0, 0);
        acct = __builtin_amdgcn_mfma_f32_16x16x32_bf16(a_t, bt_[ks], acct, 0, 0, 0);
    }
    #pragma unroll
    for (int j = 0; j < 4; ++j){
        int rr = r0 + lk * 4 + j;
        if (rr < n){
            unsigned pv = (unsigned)f2bf(accs[j]) | ((unsigned)f2bf(acct[j]) << 16);
            GSp[(size_t)rr * 16 + lr] = pv;
        }
    }
}

// ---------------- fused: SPMM-K + softmax (both branches) + cluster/con stats --------
__global__ __launch_bounds__(256) void spmm_k2_kernel(
        const unsigned* __restrict__ GSp,
        const int* __restrict__ roff, const uint2* __restrict__ csr,
        const float* __restrict__ bsv, const float* __restrict__ btv,
        float* __restrict__ asg, float* __restrict__ red, int n){
    int tid  = threadIdx.x;
    int wid  = tid >> 6, lane = tid & 63;
    int slot = lane >> 4, j = lane & 15;
    float bs_ = bsv[j], bt_ = btv[j];
    float cs_l = 0.f, con_l = 0.f;

    int rstride = gridDim.x * 4;
    for (int r = blockIdx.x * 4 + wid; r < n; r += rstride){
        int e0 = roff[r], e1 = roff[r + 1];
        float as_ = 0.f, at_ = 0.f;
        for (int e = e0 + slot; e < e1; e += 4){
            uint2 c = csr[e];
            float w = __uint_as_float(c.y);
            unsigned v = GSp[(size_t)c.x * 16 + j];
            as_ = fmaf(w, bflo(v), as_);
            at_ = fmaf(w, bfhi(v), at_);
        }
        as_ += __shfl_xor(as_, 16); as_ += __shfl_xor(as_, 32);
        at_ += __shfl_xor(at_, 16); at_ += __shfl_xor(at_, 32);
        float xs = selu1(as_ + bs_);
        float xt = selu1(at_ + bt_);
        float ms = xs, mt = xt;
        #pragma unroll
        for (int off = 8; off >= 1; off >>= 1){
            ms = fmaxf(ms, __shfl_xor(ms, off));
            mt = fmaxf(mt, __shfl_xor(mt, off));
        }
        float es = expf(xs - ms), et = expf(xt - mt);
        float ss = es, st = et;
        #pragma unroll
        for (int off = 8; off >= 1; off >>= 1){
            ss += __shfl_xor(ss, off);
            st += __shfl_xor(st, off);
        }
        float a = es / ss, b = et / st;
        if (slot == 0) asg[(size_t)r * 16 + j] = a;
        cs_l += a;
        float dot = a * b, na = a * a, nb = b * b;
        #pragma unroll
        for (int off = 8; off >= 1; off >>= 1){
            dot += __shfl_xor(dot, off);
            na  += __shfl_xor(na, off);
            nb  += __shfl_xor(nb, off);
        }
        if (j == 0){
            na = fmaxf(sqrtf(na), 1e-12f);
            nb = fmaxf(sqrtf(nb), 1e-12f);
            con_l += 2.f - 2.f * dot / (na * nb);
        }
    }

    // slots hold exact duplicates -> combine then scale by 1/4
    cs_l  += __shfl_xor(cs_l, 16);  cs_l  += __shfl_xor(cs_l, 32);  cs_l  *= 0.25f;
    con_l += __shfl_xor(con_l, 16); con_l += __shfl_xor(con_l, 32); con_l *= 0.25f;

    __shared__ float part[4][17];
    if (lane < 16) part[wid][lane] = cs_l;
    if (lane == 0) part[wid][16]   = con_l;
    __syncthreads();
    if (tid < 16){
        float s = part[0][tid] + part[1][tid] + part[2][tid] + part[3][tid];
        atomicAdd(&red[(16 + tid) * RSTRIDE], s);
    } else if (tid == 16){
        float s = part[0][16] + part[1][16] + part[2][16] + part[3][16];
        atomicAdd(&red[32 * RSTRIDE], s);
    }
}

// ---------------- per-edge: trace + nl[k] = sum_e S[dst_e][k] ----------------
__global__ __launch_bounds__(256) void edge_trace_kernel(const int* __restrict__ src,
        const int* __restrict__ dst, const float* __restrict__ as_,
        float* __restrict__ red, int E){
    int tid    = blockIdx.x * blockDim.x + threadIdx.x;
    int stride = gridDim.x * blockDim.x;
    float dot = 0.f;
    float nl[16] = {};
    for (int i = tid; i < E; i += stride){
        const float4* pa = reinterpret_cast<const float4*>(as_ + (size_t)src[i] * 16);
        const float4* pb = reinterpret_cast<const float4*>(as_ + (size_t)dst[i] * 16);
        #pragma unroll
        for (int q = 0; q < 4; ++q){
            float4 va = pa[q]; float4 vb = pb[q];
            dot = fmaf(va.x, vb.x, dot); dot = fmaf(va.y, vb.y, dot);
            dot = fmaf(va.z, vb.z, dot); dot = fmaf(va.w, vb.w, dot);
            nl[q*4+0] += vb.x; nl[q*4+1] += vb.y;
            nl[q*4+2] += vb.z; nl[q*4+3] += vb.w;
        }
    }
    #pragma unroll
    for (int off = 1; off < 64; off <<= 1){
        dot += __shfl_xor(dot, off);
        #pragma unroll
        for (int k = 0; k < 16; ++k) nl[k] += __shfl_xor(nl[k], off);
    }
    __shared__ float part[4][17];
    int wid = threadIdx.x >> 6, lane = threadIdx.x & 63;
    if (lane == 0){
        #pragma unroll
        for (int k = 0; k < 16; ++k) part[wid][k] = nl[k];
        part[wid][16] = dot;
    }
    __syncthreads();
    int t = threadIdx.x;
    if (t < 16){
        float s = part[0][t] + part[1][t] + part[2][t] + part[3][t];
        atomicAdd(&red[t * RSTRIDE], s);
    } else if (t == 16){
        float s = part[0][16] + part[1][16] + part[2][16] + part[3][16];
        atomicAdd(&red[33 * RSTRIDE], s);
    }
}

// ---------------- finalize ----------------
__global__ void finalize_kernel(const float* __restrict__ red, float* __restrict__ out,
                                int n, int E){
    float trace = red[33 * RSTRIDE];
    float nl2 = 0.f, cs2 = 0.f;
    #pragma unroll
    for (int k = 0; k < 16; ++k){
        nl2 = fmaf(red[k * RSTRIDE],        red[k * RSTRIDE],        nl2);
        cs2 = fmaf(red[(16 + k) * RSTRIDE], red[(16 + k) * RSTRIDE], cs2);
    }
    float twoE = 2.f * (float)E;
    float spectral = -(trace - nl2 / twoE) / twoE;
    float cluster  = sqrtf(cs2) / (float)n * 4.f - 1.f;
    float con      = red[32 * RSTRIDE] / (float)n;
    out[0] = spectral + cluster + con;
}

extern "C" void kernel_launch(void* const* d_in, const int* in_sizes, int n_in,
                              void* d_out, int out_size, void* d_ws, size_t ws_size,
                              hipStream_t stream){
    const int*   esrc = (const int*)d_in[0];
    const int*   edst = (const int*)d_in[1];
    const float* ew   = (const float*)d_in[2];
    const float* feat = (const float*)d_in[3];
    const float* faug = (const float*)d_in[4];
    const float* W1   = (const float*)d_in[5];
    const float* b1   = (const float*)d_in[6];
    const float* Wsm  = (const float*)d_in[7];
    const float* bsv  = (const float*)d_in[8];
    const float* Wtm  = (const float*)d_in[9];
    const float* btv  = (const float*)d_in[10];
    int E = in_sizes[0];
    int N = in_sizes[3] / Fdim;

    char* ws = (char*)d_ws;
    size_t off = 0;
    auto alloc = [&](size_t bytes) -> char* {
        char* p = ws + off;
        off = (off + bytes + 255) & ~(size_t)255;
        return p;
    };
    int nbuck = (N + 255) >> 8;
    unsigned char* XWp = (unsigned char*)alloc((size_t)N * 512);  // fp8 [N][512B]
    ushort*   Gs    = (ushort*)alloc((size_t)N * Hdim * 2);
    ushort*   Gt    = (ushort*)alloc((size_t)N * Hdim * 2);
    unsigned* GSp   = (unsigned*)alloc((size_t)N * Kc * 4);
    float*    ASG_S = (float*)alloc((size_t)N * Kc * 4);
    ushort*   WT    = (ushort*)alloc((size_t)256 * 256 * 2);
    ushort*   WsT   = (ushort*)alloc((size_t)16 * 256 * 2);
    ushort*   WtT   = (ushort*)alloc((size_t)16 * 256 * 2);
    int*      ROFF  = (int*)alloc((size_t)(N + 1) * 4);
    int*      BBASE = (int*)alloc((size_t)(nbuck + 1) * 4);
    int*      BCNT  = (int*)alloc((size_t)nbuck * 32 * 4);
    int*      BSRC  = (int*)alloc((size_t)nbuck * BCAP * 4);
    uint2*    BDW   = (uint2*)alloc((size_t)nbuck * BCAP * 8);
    uint2*    CSR8  = (uint2*)alloc((size_t)E * 8);
    float*    RED   = (float*)alloc((size_t)NRED * RSTRIDE * 4);

    hipMemsetAsync(BCNT, 0, (size_t)nbuck * 32 * 4, stream);
    hipMemsetAsync(RED, 0, (size_t)NRED * RSTRIDE * 4, stream);

    castw_kernel<<<dim3(16, 16), dim3(16, 16), 0, stream>>>(W1, WT);
    castwk_kernel<<<1, 256, 0, stream>>>(Wsm, Wtm, WsT, WtT);
    bin_kernel<<<256, 256, 0, stream>>>(esrc, edst, ew, BCNT, BSRC, BDW, E, nbuck);
    bbase_kernel<<<1, 256, 0, stream>>>(BCNT, BBASE, ROFF, nbuck, N);
    csr_build_kernel<<<nbuck, 256, 0, stream>>>(BCNT, BBASE, BSRC, BDW, ROFF, CSR8, N);

    dim3 gg(2, (N + 127) / 128, 2);
    gemm_xw_kernel<<<gg, 256, 0, stream>>>(feat, faug, WT, XWp, N);

    spmm_h2_kernel<<<(N + 3) / 4, 256, 0, stream>>>(XWp, ROFF, CSR8, b1, Gs, Gt, N);

    int nw = (N + 15) / 16;
    gemm_k2_kernel<<<(nw + 3) / 4, 256, 0, stream>>>(Gs, Gt, WsT, WtT, GSp, N);

    spmm_k2_kernel<<<2048, 256, 0, stream>>>(GSp, ROFF, CSR8, bsv, btv,
                                             ASG_S, RED, N);

    edge_trace_kernel<<<256, 256, 0, stream>>>(esrc, edst, ASG_S, RED, E);
    finalize_kernel<<<1, 1, 0, stream>>>(RED, (float*)d_out, N, E);
}

// Round 16
// 247.806 us; speedup vs baseline: 1.3996x; 1.1752x over previous
//
#include <hip/hip_runtime.h>
#include <math.h>

constexpr int Fdim = 256;
constexpr int Hdim = 256;
constexpr int Kc   = 16;

constexpr int RSTRIDE = 32;
constexpr int NRED    = 34;   // 0..15 nl, 16..31 cluster_sizes, 32 con, 33 trace
constexpr int BCAP    = 5120; // bucket capacity (mean 4096, 16 sigma slack)

typedef __attribute__((ext_vector_type(8))) short s8v;   // 8 bf16 (4 VGPRs)
typedef __attribute__((ext_vector_type(4))) float f4v;   // 4 fp32 acc

__device__ __forceinline__ float selu1(float x){
    const float scale = 1.0507009873554805f;
    const float alpha = 1.6732632423543772f;
    return scale * (x > 0.f ? x : alpha * expm1f(x));
}

__device__ __forceinline__ ushort f2bf(float x){
    union { float f; unsigned u; } c; c.f = x;
    unsigned r = c.u + 0x7fffu + ((c.u >> 16) & 1u);   // RNE
    return (ushort)(r >> 16);
}

__device__ __forceinline__ float bflo(unsigned v){
    union { unsigned u; float f; } c; c.u = v << 16; return c.f;
}
__device__ __forceinline__ float bfhi(unsigned v){
    union { unsigned u; float f; } c; c.u = v & 0xffff0000u; return c.f;
}

// fp8 e4m3 encode via HW converter (RNE)
__device__ __forceinline__ unsigned char f2fp8(float x){
    int v = __builtin_amdgcn_cvt_pk_fp8_f32(x, x, 0, false);
    return (unsigned char)(v & 0xff);
}

// ---------------- CSR build phase A: LDS-staged binning ----------
__global__ __launch_bounds__(256) void bin_kernel(
        const int* __restrict__ src, const int* __restrict__ dst,
        const float* __restrict__ w,
        int* __restrict__ bcnt,
        int* __restrict__ bsrc, uint2* __restrict__ bdw, int E, int nbuck){
    __shared__ int hist[256];
    __shared__ int base[256];
    __shared__ int cur[256];
    int t = threadIdx.x;
    int chunk = (E + gridDim.x - 1) / gridDim.x;
    int lo = blockIdx.x * chunk;
    int hi = min(lo + chunk, E);
    hist[t] = 0;
    __syncthreads();
    for (int i = lo + t; i < hi; i += 256)
        atomicAdd(&hist[src[i] >> 8], 1);
    __syncthreads();
    if (t < nbuck && hist[t] > 0)
        base[t] = atomicAdd(&bcnt[t * 32], hist[t]);
    cur[t] = 0;
    __syncthreads();
    for (int i = lo + t; i < hi; i += 256){
        int s = src[i], d = dst[i];
        float wv = w[i];
        int b = s >> 8;
        int p = base[b] + atomicAdd(&cur[b], 1);
        if (p < BCAP){
            bsrc[(size_t)b * BCAP + p] = s;
            bdw[(size_t)b * BCAP + p]  = make_uint2((unsigned)d, __float_as_uint(wv));
        }
    }
}

// ---------------- bucket-base scan (single block) + roff[n] ----------------
__global__ __launch_bounds__(256) void bbase_kernel(const int* __restrict__ bcnt,
        int* __restrict__ bbase, int* __restrict__ roff, int nbuck, int n){
    __shared__ int s[256];
    int t = threadIdx.x;
    int v = (t < nbuck) ? min(bcnt[t * 32], BCAP) : 0;
    s[t] = v;
    __syncthreads();
    for (int off = 1; off < 256; off <<= 1){
        int x = (t >= off) ? s[t - off] : 0;
        __syncthreads();
        s[t] += x;
        __syncthreads();
    }
    if (t < nbuck) bbase[t] = s[t] - v;   // exclusive
    if (t == 255) roff[n] = s[255];       // total = E
}

// ---------------- per-bucket: src hist + scan -> roff slice, then scatter ----------
__global__ __launch_bounds__(256) void csr_build_kernel(
        const int* __restrict__ bcnt, const int* __restrict__ bbase,
        const int* __restrict__ bsrc, const uint2* __restrict__ bdw,
        int* __restrict__ roff, uint2* __restrict__ csr, int n){
    __shared__ int hist[256];
    __shared__ int loc[256];
    __shared__ int cur[256];
    int b = blockIdx.x, t = threadIdx.x;
    int cnt  = min(bcnt[b * 32], BCAP);
    int base = bbase[b];
    hist[t] = 0;
    __syncthreads();
    for (int i = t; i < cnt; i += 256)
        atomicAdd(&hist[bsrc[(size_t)b * BCAP + i] & 255], 1);
    __syncthreads();
    int v = hist[t];
    loc[t] = v;
    __syncthreads();
    for (int off = 1; off < 256; off <<= 1){
        int x = (t >= off) ? loc[t - off] : 0;
        __syncthreads();
        loc[t] += x;
        __syncthreads();
    }
    int gi = b * 256 + t;
    if (gi < n) roff[gi] = base + loc[t] - v;
    cur[t] = 0;
    __syncthreads();
    for (int i = t; i < cnt; i += 256){
        int s   = bsrc[(size_t)b * BCAP + i];
        int idx = s & 255;
        int p = base + (loc[idx] - hist[idx]) + atomicAdd(&cur[idx], 1);
        csr[p] = bdw[(size_t)b * BCAP + i];
    }
}

// ---------------- W1 transpose-cast: Wt[n][k] = bf16(W1[k][n]) ----------------
__global__ void castw_kernel(const float* __restrict__ W, ushort* __restrict__ Wt){
    __shared__ float t[16][17];
    int tx = threadIdx.x, ty = threadIdx.y;
    int k  = blockIdx.y * 16 + ty;
    int nn = blockIdx.x * 16 + tx;
    t[ty][tx] = W[k * 256 + nn];
    __syncthreads();
    int n2 = blockIdx.x * 16 + ty;
    int k2 = blockIdx.y * 16 + tx;
    Wt[n2 * 256 + k2] = f2bf(t[tx][ty]);
}

// ---------------- Ws/Wt transpose-cast ----------------
__global__ void castwk_kernel(const float* __restrict__ Ws, const float* __restrict__ Wt,
                              ushort* __restrict__ WsT, ushort* __restrict__ WtT){
    int h = threadIdx.x;   // 0..255
    #pragma unroll
    for (int c = 0; c < 16; ++c){
        WsT[c * 256 + h] = f2bf(Ws[h * 16 + c]);
        WtT[c * 256 + h] = f2bf(Wt[h * 16 + c]);
    }
}

// ---------------- MFMA bf16 GEMM: 2 K-phases, 32 KB LDS, launch_bounds(256,2) ----------
// grid = (2 col-halves, ceil(M/128), 2 branches); 256 thr.
// 32 KB LDS -> 4-5 blocks/CU; VGPR cap 128 (min-waves=2) -> no spill -> ~16 waves/CU.
__global__ __launch_bounds__(256, 2) void gemm_xw_kernel(
        const float* __restrict__ A0, const float* __restrict__ A1,
        const ushort* __restrict__ Bt,
        unsigned char* __restrict__ C8, int M){
    __shared__ ushort blds[16384];   // 32 KB: 128 cols x 128 k (swizzled)
    int tid = threadIdx.x;
    int n0  = blockIdx.x * 128;
    int bm  = blockIdx.y * 128;
    const float* A = blockIdx.z ? A1 : A0;
    int halfoff = blockIdx.z * 256;

    int w = tid >> 6, l = tid & 63;
    int lr = l & 15, lk = l >> 4;

    int r0 = bm + w * 32 + lr;
    int r1 = r0 + 16;
    int rc0 = min(r0, M - 1), rc1 = min(r1, M - 1);

    f4v acc[2][8];
    #pragma unroll
    for (int m = 0; m < 2; ++m)
        #pragma unroll
        for (int t = 0; t < 8; ++t)
            acc[m][t] = (f4v){0.f, 0.f, 0.f, 0.f};

    for (int kp = 0; kp < 2; ++kp){
        // ---- stage B: 128 cols x 128 k = 2048 chunks of 16B ----
        #pragma unroll
        for (int j = 0; j < 8; ++j){
            int c  = j * 256 + tid;
            int nl = c >> 4, kc = c & 15;     // col, 16B-chunk within 256B row
            uint4 v = *reinterpret_cast<const uint4*>(
                Bt + (((size_t)(n0 + nl)) << 8) + kp * 128 + (kc << 3));
            unsigned boff = (unsigned)(((nl << 8) + (kc << 4)) ^ ((nl & 7) << 4));
            *reinterpret_cast<uint4*>(reinterpret_cast<char*>(blds) + boff) = v;
        }

        // ---- A loads for this k-phase (overlap with staging before barrier) ----
        const float* a0 = A + (size_t)rc0 * 256 + kp * 128 + lk * 8;
        const float* a1 = A + (size_t)rc1 * 256 + kp * 128 + lk * 8;
        s8v af0[4], af1[4];
        #pragma unroll
        for (int ks = 0; ks < 4; ++ks){
            float4 x0 = *reinterpret_cast<const float4*>(a0 + ks * 32);
            float4 x1 = *reinterpret_cast<const float4*>(a0 + ks * 32 + 4);
            af0[ks][0] = (short)f2bf(x0.x); af0[ks][1] = (short)f2bf(x0.y);
            af0[ks][2] = (short)f2bf(x0.z); af0[ks][3] = (short)f2bf(x0.w);
            af0[ks][4] = (short)f2bf(x1.x); af0[ks][5] = (short)f2bf(x1.y);
            af0[ks][6] = (short)f2bf(x1.z); af0[ks][7] = (short)f2bf(x1.w);
            float4 y0 = *reinterpret_cast<const float4*>(a1 + ks * 32);
            float4 y1 = *reinterpret_cast<const float4*>(a1 + ks * 32 + 4);
            af1[ks][0] = (short)f2bf(y0.x); af1[ks][1] = (short)f2bf(y0.y);
            af1[ks][2] = (short)f2bf(y0.z); af1[ks][3] = (short)f2bf(y0.w);
            af1[ks][4] = (short)f2bf(y1.x); af1[ks][5] = (short)f2bf(y1.y);
            af1[ks][6] = (short)f2bf(y1.z); af1[ks][7] = (short)f2bf(y1.w);
        }
        __syncthreads();

        #pragma unroll
        for (int ks = 0; ks < 4; ++ks){
            #pragma unroll
            for (int t = 0; t < 8; ++t){
                int nl = t * 16 + lr;
                unsigned boff = (unsigned)(((nl << 8) + ((ks * 4 + lk) << 4)) ^ ((nl & 7) << 4));
                s8v bf = *reinterpret_cast<const s8v*>(reinterpret_cast<const char*>(blds) + boff);
                acc[0][t] = __builtin_amdgcn_mfma_f32_16x16x32_bf16(af0[ks], bf, acc[0][t], 0, 0, 0);
                acc[1][t] = __builtin_amdgcn_mfma_f32_16x16x32_bf16(af1[ks], bf, acc[1][t], 0, 0, 0);
            }
        }
        if (kp == 0) __syncthreads();   // drain reads before restage
    }

    // fp8 store: byte addr = row*512 + halfoff + col
    #pragma unroll
    for (int m = 0; m < 2; ++m){
        #pragma unroll
        for (int t = 0; t < 8; ++t){
            int col = n0 + t * 16 + lr;
            #pragma unroll
            for (int j = 0; j < 4; ++j){
                int row = bm + w * 32 + m * 16 + lk * 4 + j;
                if (row < M) C8[(size_t)row * 512 + halfoff + col] = f2fp8(acc[m][t][j]);
            }
        }
    }
}

// ---------------- fused SPMM over H=256 (student+teacher), fp8 table, + bias + selu ----
__global__ __launch_bounds__(256) void spmm_h2_kernel(
        const unsigned char* __restrict__ XWp,
        const int* __restrict__ roff, const uint2* __restrict__ csr,
        const float* __restrict__ b1,
        ushort* __restrict__ Gs, ushort* __restrict__ Gt, int n){
    int wid = threadIdx.x >> 6, lane = threadIdx.x & 63;
    int r = blockIdx.x * 4 + wid;
    if (r >= n) return;
    int half = lane >> 5;          // 0 = student, 1 = teacher
    int hl   = lane & 31;          // col group: cols hl*8 .. hl*8+7
    const unsigned char* base = XWp + lane * 8;
    int e0 = roff[r], e1 = roff[r + 1];
    float acc[8] = {};

    #define ACCUM8(V, W) do{                                                      \
        auto fa_ = __builtin_amdgcn_cvt_pk_f32_fp8((V).x, false);                 \
        acc[0] = fmaf((W), fa_[0], acc[0]); acc[1] = fmaf((W), fa_[1], acc[1]);   \
        auto fb_ = __builtin_amdgcn_cvt_pk_f32_fp8((V).x, true);                  \
        acc[2] = fmaf((W), fb_[0], acc[2]); acc[3] = fmaf((W), fb_[1], acc[3]);   \
        auto fc_ = __builtin_amdgcn_cvt_pk_f32_fp8((V).y, false);                 \
        acc[4] = fmaf((W), fc_[0], acc[4]); acc[5] = fmaf((W), fc_[1], acc[5]);   \
        auto fd_ = __builtin_amdgcn_cvt_pk_f32_fp8((V).y, true);                  \
        acc[6] = fmaf((W), fd_[0], acc[6]); acc[7] = fmaf((W), fd_[1], acc[7]);   \
    }while(0)

    int e = e0;
    for (; e + 7 < e1; e += 8){
        uint2 c0 = csr[e],     c1 = csr[e + 1];
        uint2 c2 = csr[e + 2], c3 = csr[e + 3];
        uint2 c4 = csr[e + 4], c5 = csr[e + 5];
        uint2 c6 = csr[e + 6], c7 = csr[e + 7];
        uint2 v0 = *reinterpret_cast<const uint2*>(base + ((size_t)c0.x << 9));
        uint2 v1 = *reinterpret_cast<const uint2*>(base + ((size_t)c1.x << 9));
        uint2 v2 = *reinterpret_cast<const uint2*>(base + ((size_t)c2.x << 9));
        uint2 v3 = *reinterpret_cast<const uint2*>(base + ((size_t)c3.x << 9));
        uint2 v4 = *reinterpret_cast<const uint2*>(base + ((size_t)c4.x << 9));
        uint2 v5 = *reinterpret_cast<const uint2*>(base + ((size_t)c5.x << 9));
        uint2 v6 = *reinterpret_cast<const uint2*>(base + ((size_t)c6.x << 9));
        uint2 v7 = *reinterpret_cast<const uint2*>(base + ((size_t)c7.x << 9));
        ACCUM8(v0, __uint_as_float(c0.y)); ACCUM8(v1, __uint_as_float(c1.y));
        ACCUM8(v2, __uint_as_float(c2.y)); ACCUM8(v3, __uint_as_float(c3.y));
        ACCUM8(v4, __uint_as_float(c4.y)); ACCUM8(v5, __uint_as_float(c5.y));
        ACCUM8(v6, __uint_as_float(c6.y)); ACCUM8(v7, __uint_as_float(c7.y));
    }
    for (; e + 3 < e1; e += 4){
        uint2 c0 = csr[e],     c1 = csr[e + 1];
        uint2 c2 = csr[e + 2], c3 = csr[e + 3];
        uint2 v0 = *reinterpret_cast<const uint2*>(base + ((size_t)c0.x << 9));
        uint2 v1 = *reinterpret_cast<const uint2*>(base + ((size_t)c1.x << 9));
        uint2 v2 = *reinterpret_cast<const uint2*>(base + ((size_t)c2.x << 9));
        uint2 v3 = *reinterpret_cast<const uint2*>(base + ((size_t)c3.x << 9));
        ACCUM8(v0, __uint_as_float(c0.y)); ACCUM8(v1, __uint_as_float(c1.y));
        ACCUM8(v2, __uint_as_float(c2.y)); ACCUM8(v3, __uint_as_float(c3.y));
    }
    for (; e < e1; ++e){
        uint2 c = csr[e];
        uint2 v = *reinterpret_cast<const uint2*>(base + ((size_t)c.x << 9));
        ACCUM8(v, __uint_as_float(c.y));
    }
    #undef ACCUM8

    const float* bp = b1 + hl * 8;
    float4 bb0 = *reinterpret_cast<const float4*>(bp);
    float4 bb1 = *reinterpret_cast<const float4*>(bp + 4);
    float bv[8] = {bb0.x, bb0.y, bb0.z, bb0.w, bb1.x, bb1.y, bb1.z, bb1.w};
    ushort o[8];
    #pragma unroll
    for (int q = 0; q < 8; ++q) o[q] = f2bf(selu1(acc[q] + bv[q]));
    uint4 ov = *reinterpret_cast<const uint4*>(o);
    ushort* gout = (half ? Gt : Gs) + (size_t)r * Hdim + hl * 8;
    *reinterpret_cast<uint4*>(gout) = ov;
}

// ---------------- fused MFMA: GS = pack(Gs@Ws, Gt@Wt) bf16   [N,256]x[256,16] ----------
__global__ __launch_bounds__(256) void gemm_k2_kernel(
        const ushort* __restrict__ Gs, const ushort* __restrict__ Gt,
        const ushort* __restrict__ WsT, const ushort* __restrict__ WtT,
        unsigned* __restrict__ GSp, int n){
    int wv = blockIdx.x * 4 + (threadIdx.x >> 6);
    int l  = threadIdx.x & 63;
    int lr = l & 15, lk = l >> 4;
    int nw = (n + 15) >> 4;
    if (wv >= nw) return;
    int r0 = wv * 16;

    s8v bs_[8], bt_[8];
    #pragma unroll
    for (int ks = 0; ks < 8; ++ks){
        bs_[ks] = *reinterpret_cast<const s8v*>(WsT + lr * 256 + ks * 32 + lk * 8);
        bt_[ks] = *reinterpret_cast<const s8v*>(WtT + lr * 256 + ks * 32 + lk * 8);
    }

    f4v accs = (f4v){0.f,0.f,0.f,0.f}, acct = (f4v){0.f,0.f,0.f,0.f};
    int row = min(r0 + lr, n - 1);
    const ushort* gsrow = Gs + (size_t)row * 256 + lk * 8;
    const ushort* gtrow = Gt + (size_t)row * 256 + lk * 8;
    #pragma unroll
    for (int ks = 0; ks < 8; ++ks){
        s8v a_s = *reinterpret_cast<const s8v*>(gsrow + ks * 32);
        s8v a_t = *reinterpret_cast<const s8v*>(gtrow + ks * 32);
        accs = __builtin_amdgcn_mfma_f32_16x16x32_bf16(a_s, bs_[ks], accs, 0, 0, 0);
        acct = __builtin_amdgcn_mfma_f32_16x16x32_bf16(a_t, bt_[ks], acct, 0, 0, 0);
    }
    #pragma unroll
    for (int j = 0; j < 4; ++j){
        int rr = r0 + lk * 4 + j;
        if (rr < n){
            unsigned pv = (unsigned)f2bf(accs[j]) | ((unsigned)f2bf(acct[j]) << 16);
            GSp[(size_t)rr * 16 + lr] = pv;
        }
    }
}

// ---------------- fused: SPMM-K + softmax (both branches) + cluster/con stats --------
__global__ __launch_bounds__(256) void spmm_k2_kernel(
        const unsigned* __restrict__ GSp,
        const int* __restrict__ roff, const uint2* __restrict__ csr,
        const float* __restrict__ bsv, const float* __restrict__ btv,
        float* __restrict__ asg, float* __restrict__ red, int n){
    int tid  = threadIdx.x;
    int wid  = tid >> 6, lane = tid & 63;
    int slot = lane >> 4, j = lane & 15;
    float bs_ = bsv[j], bt_ = btv[j];
    float cs_l = 0.f, con_l = 0.f;

    int rstride = gridDim.x * 4;
    for (int r = blockIdx.x * 4 + wid; r < n; r += rstride){
        int e0 = roff[r], e1 = roff[r + 1];
        float as_ = 0.f, at_ = 0.f;
        for (int e = e0 + slot; e < e1; e += 4){
            uint2 c = csr[e];
            float w = __uint_as_float(c.y);
            unsigned v = GSp[(size_t)c.x * 16 + j];
            as_ = fmaf(w, bflo(v), as_);
            at_ = fmaf(w, bfhi(v), at_);
        }
        as_ += __shfl_xor(as_, 16); as_ += __shfl_xor(as_, 32);
        at_ += __shfl_xor(at_, 16); at_ += __shfl_xor(at_, 32);
        float xs = selu1(as_ + bs_);
        float xt = selu1(at_ + bt_);
        float ms = xs, mt = xt;
        #pragma unroll
        for (int off = 8; off >= 1; off >>= 1){
            ms = fmaxf(ms, __shfl_xor(ms, off));
            mt = fmaxf(mt, __shfl_xor(mt, off));
        }
        float es = expf(xs - ms), et = expf(xt - mt);
        float ss = es, st = et;
        #pragma unroll
        for (int off = 8; off >= 1; off >>= 1){
            ss += __shfl_xor(ss, off);
            st += __shfl_xor(st, off);
        }
        float a = es / ss, b = et / st;
        if (slot == 0) asg[(size_t)r * 16 + j] = a;
        cs_l += a;
        float dot = a * b, na = a * a, nb = b * b;
        #pragma unroll
        for (int off = 8; off >= 1; off >>= 1){
            dot += __shfl_xor(dot, off);
            na  += __shfl_xor(na, off);
            nb  += __shfl_xor(nb, off);
        }
        if (j == 0){
            na = fmaxf(sqrtf(na), 1e-12f);
            nb = fmaxf(sqrtf(nb), 1e-12f);
            con_l += 2.f - 2.f * dot / (na * nb);
        }
    }

    // slots hold exact duplicates -> combine then scale by 1/4
    cs_l  += __shfl_xor(cs_l, 16);  cs_l  += __shfl_xor(cs_l, 32);  cs_l  *= 0.25f;
    con_l += __shfl_xor(con_l, 16); con_l += __shfl_xor(con_l, 32); con_l *= 0.25f;

    __shared__ float part[4][17];
    if (lane < 16) part[wid][lane] = cs_l;
    if (lane == 0) part[wid][16]   = con_l;
    __syncthreads();
    if (tid < 16){
        float s = part[0][tid] + part[1][tid] + part[2][tid] + part[3][tid];
        atomicAdd(&red[(16 + tid) * RSTRIDE], s);
    } else if (tid == 16){
        float s = part[0][16] + part[1][16] + part[2][16] + part[3][16];
        atomicAdd(&red[32 * RSTRIDE], s);
    }
}

// ---------------- per-edge: trace + nl[k] = sum_e S[dst_e][k] ----------------
__global__ __launch_bounds__(256) void edge_trace_kernel(const int* __restrict__ src,
        const int* __restrict__ dst, const float* __restrict__ as_,
        float* __restrict__ red, int E){
    int tid    = blockIdx.x * blockDim.x + threadIdx.x;
    int stride = gridDim.x * blockDim.x;
    float dot = 0.f;
    float nl[16] = {};
    for (int i = tid; i < E; i += stride){
        const float4* pa = reinterpret_cast<const float4*>(as_ + (size_t)src[i] * 16);
        const float4* pb = reinterpret_cast<const float4*>(as_ + (size_t)dst[i] * 16);
        #pragma unroll
        for (int q = 0; q < 4; ++q){
            float4 va = pa[q]; float4 vb = pb[q];
            dot = fmaf(va.x, vb.x, dot); dot = fmaf(va.y, vb.y, dot);
            dot = fmaf(va.z, vb.z, dot); dot = fmaf(va.w, vb.w, dot);
            nl[q*4+0] += vb.x; nl[q*4+1] += vb.y;
            nl[q*4+2] += vb.z; nl[q*4+3] += vb.w;
        }
    }
    #pragma unroll
    for (int off = 1; off < 64; off <<= 1){
        dot += __shfl_xor(dot, off);
        #pragma unroll
        for (int k = 0; k < 16; ++k) nl[k] += __shfl_xor(nl[k], off);
    }
    __shared__ float part[4][17];
    int wid = threadIdx.x >> 6, lane = threadIdx.x & 63;
    if (lane == 0){
        #pragma unroll
        for (int k = 0; k < 16; ++k) part[wid][k] = nl[k];
        part[wid][16] = dot;
    }
    __syncthreads();
    int t = threadIdx.x;
    if (t < 16){
        float s = part[0][t] + part[1][t] + part[2][t] + part[3][t];
        atomicAdd(&red[t * RSTRIDE], s);
    } else if (t == 16){
        float s = part[0][16] + part[1][16] + part[2][16] + part[3][16];
        atomicAdd(&red[33 * RSTRIDE], s);
    }
}

// ---------------- finalize ----------------
__global__ void finalize_kernel(const float* __restrict__ red, float* __restrict__ out,
                                int n, int E){
    float trace = red[33 * RSTRIDE];
    float nl2 = 0.f, cs2 = 0.f;
    #pragma unroll
    for (int k = 0; k < 16; ++k){
        nl2 = fmaf(red[k * RSTRIDE],        red[k * RSTRIDE],        nl2);
        cs2 = fmaf(red[(16 + k) * RSTRIDE], red[(16 + k) * RSTRIDE], cs2);
    }
    float twoE = 2.f * (float)E;
    float spectral = -(trace - nl2 / twoE) / twoE;
    float cluster  = sqrtf(cs2) / (float)n * 4.f - 1.f;
    float con      = red[32 * RSTRIDE] / (float)n;
    out[0] = spectral + cluster + con;
}

extern "C" void kernel_launch(void* const* d_in, const int* in_sizes, int n_in,
                              void* d_out, int out_size, void* d_ws, size_t ws_size,
                              hipStream_t stream){
    const int*   esrc = (const int*)d_in[0];
    const int*   edst = (const int*)d_in[1];
    const float* ew   = (const float*)d_in[2];
    const float* feat = (const float*)d_in[3];
    const float* faug = (const float*)d_in[4];
    const float* W1   = (const float*)d_in[5];
    const float* b1   = (const float*)d_in[6];
    const float* Wsm  = (const float*)d_in[7];
    const float* bsv  = (const float*)d_in[8];
    const float* Wtm  = (const float*)d_in[9];
    const float* btv  = (const float*)d_in[10];
    int E = in_sizes[0];
    int N = in_sizes[3] / Fdim;

    char* ws = (char*)d_ws;
    size_t off = 0;
    auto alloc = [&](size_t bytes) -> char* {
        char* p = ws + off;
        off = (off + bytes + 255) & ~(size_t)255;
        return p;
    };
    int nbuck = (N + 255) >> 8;
    unsigned char* XWp = (unsigned char*)alloc((size_t)N * 512);  // fp8 [N][512B]
    ushort*   Gs    = (ushort*)alloc((size_t)N * Hdim * 2);
    ushort*   Gt    = (ushort*)alloc((size_t)N * Hdim * 2);
    unsigned* GSp   = (unsigned*)alloc((size_t)N * Kc * 4);
    float*    ASG_S = (float*)alloc((size_t)N * Kc * 4);
    ushort*   WT    = (ushort*)alloc((size_t)256 * 256 * 2);
    ushort*   WsT   = (ushort*)alloc((size_t)16 * 256 * 2);
    ushort*   WtT   = (ushort*)alloc((size_t)16 * 256 * 2);
    int*      ROFF  = (int*)alloc((size_t)(N + 1) * 4);
    int*      BBASE = (int*)alloc((size_t)(nbuck + 1) * 4);
    int*      BCNT  = (int*)alloc((size_t)nbuck * 32 * 4);
    int*      BSRC  = (int*)alloc((size_t)nbuck * BCAP * 4);
    uint2*    BDW   = (uint2*)alloc((size_t)nbuck * BCAP * 8);
    uint2*    CSR8  = (uint2*)alloc((size_t)E * 8);
    float*    RED   = (float*)alloc((size_t)NRED * RSTRIDE * 4);

    hipMemsetAsync(BCNT, 0, (size_t)nbuck * 32 * 4, stream);
    hipMemsetAsync(RED, 0, (size_t)NRED * RSTRIDE * 4, stream);

    castw_kernel<<<dim3(16, 16), dim3(16, 16), 0, stream>>>(W1, WT);
    castwk_kernel<<<1, 256, 0, stream>>>(Wsm, Wtm, WsT, WtT);
    bin_kernel<<<256, 256, 0, stream>>>(esrc, edst, ew, BCNT, BSRC, BDW, E, nbuck);
    bbase_kernel<<<1, 256, 0, stream>>>(BCNT, BBASE, ROFF, nbuck, N);
    csr_build_kernel<<<nbuck, 256, 0, stream>>>(BCNT, BBASE, BSRC, BDW, ROFF, CSR8, N);

    dim3 gg(2, (N + 127) / 128, 2);
    gemm_xw_kernel<<<gg, 256, 0, stream>>>(feat, faug, WT, XWp, N);

    spmm_h2_kernel<<<(N + 3) / 4, 256, 0, stream>>>(XWp, ROFF, CSR8, b1, Gs, Gt, N);

    int nw = (N + 15) / 16;
    gemm_k2_kernel<<<(nw + 3) / 4, 256, 0, stream>>>(Gs, Gt, WsT, WtT, GSp, N);

    spmm_k2_kernel<<<2048, 256, 0, stream>>>(GSp, ROFF, CSR8, bsv, btv,
                                             ASG_S, RED, N);

    edge_trace_kernel<<<256, 256, 0, stream>>>(esrc, edst, ASG_S, RED, E);
    finalize_kernel<<<1, 1, 0, stream>>>(RED, (float*)d_out, N, E);
}

// Round 17
// 236.569 us; speedup vs baseline: 1.4661x; 1.0475x over previous
//
#include <hip/hip_runtime.h>
#include <math.h>

constexpr int Fdim = 256;
constexpr int Hdim = 256;
constexpr int Kc   = 16;

constexpr int RSTRIDE = 32;
constexpr int NRED    = 34;   // 0..15 nl, 16..31 cluster_sizes, 32 con, 33 trace
constexpr int BCAP    = 5120; // bucket capacity (mean 4096, 16 sigma slack)

typedef __attribute__((ext_vector_type(8))) short s8v;   // 8 bf16 (4 VGPRs)
typedef __attribute__((ext_vector_type(4))) float f4v;   // 4 fp32 acc

__device__ __forceinline__ float selu1(float x){
    const float scale = 1.0507009873554805f;
    const float alpha = 1.6732632423543772f;
    return scale * (x > 0.f ? x : alpha * expm1f(x));
}

__device__ __forceinline__ ushort f2bf(float x){
    union { float f; unsigned u; } c; c.f = x;
    unsigned r = c.u + 0x7fffu + ((c.u >> 16) & 1u);   // RNE
    return (ushort)(r >> 16);
}

__device__ __forceinline__ float bflo(unsigned v){
    union { unsigned u; float f; } c; c.u = v << 16; return c.f;
}
__device__ __forceinline__ float bfhi(unsigned v){
    union { unsigned u; float f; } c; c.u = v & 0xffff0000u; return c.f;
}

// fp8 e4m3 encode via HW converter (RNE)
__device__ __forceinline__ unsigned char f2fp8(float x){
    int v = __builtin_amdgcn_cvt_pk_fp8_f32(x, x, 0, false);
    return (unsigned char)(v & 0xff);
}

// ---------------- prep: castw (blocks 0..255) + castwk (block 256) ----------------
__global__ __launch_bounds__(256) void prep_kernel(
        const float* __restrict__ W1, ushort* __restrict__ WT,
        const float* __restrict__ Ws, const float* __restrict__ Wt,
        ushort* __restrict__ WsT, ushort* __restrict__ WtT){
    __shared__ float tbuf[16][17];
    int b = blockIdx.x;
    int t = threadIdx.x;
    if (b < 256){
        int bx = b & 15, by = b >> 4;
        int tx = t & 15, ty = t >> 4;
        int k  = by * 16 + ty;
        int nn = bx * 16 + tx;
        tbuf[ty][tx] = W1[k * 256 + nn];
        __syncthreads();
        int n2 = bx * 16 + ty;
        int k2 = by * 16 + tx;
        WT[n2 * 256 + k2] = f2bf(tbuf[tx][ty]);
    } else {
        int h = t;
        #pragma unroll
        for (int c = 0; c < 16; ++c){
            WsT[c * 256 + h] = f2bf(Ws[h * 16 + c]);
            WtT[c * 256 + h] = f2bf(Wt[h * 16 + c]);
        }
    }
}

// ---------------- MEGA: bin (blocks 0..255) + MFMA GEMM (blocks 256..) ----------
// bin: LDS-staged edge binning. gemm: 2 K-phases, 32 KB LDS, proven R16 body.
__global__ __launch_bounds__(256, 2) void mega_kernel(
        const int* __restrict__ esrc, const int* __restrict__ edst,
        const float* __restrict__ ew, int* __restrict__ bcnt,
        int* __restrict__ bsrc, uint2* __restrict__ bdw, int E, int nbuck,
        const float* __restrict__ A0, const float* __restrict__ A1,
        const ushort* __restrict__ Bt, unsigned char* __restrict__ C8,
        int M, int nrt){
    __shared__ char smem[32768];
    int tid = threadIdx.x;

    if (blockIdx.x < 256){
        // ---------------- bin path ----------------
        int* hist = (int*)smem;
        int* base = hist + 256;
        int* cur  = base + 256;
        int chunk = (E + 255) / 256;
        int lo = blockIdx.x * chunk;
        int hi = min(lo + chunk, E);
        hist[tid] = 0;
        __syncthreads();
        for (int i = lo + tid; i < hi; i += 256)
            atomicAdd(&hist[esrc[i] >> 8], 1);
        __syncthreads();
        if (tid < nbuck && hist[tid] > 0)
            base[tid] = atomicAdd(&bcnt[tid * 32], hist[tid]);
        cur[tid] = 0;
        __syncthreads();
        for (int i = lo + tid; i < hi; i += 256){
            int s = esrc[i], d = edst[i];
            float wv = ew[i];
            int b = s >> 8;
            int p = base[b] + atomicAdd(&cur[b], 1);
            if (p < BCAP){
                bsrc[(size_t)b * BCAP + p] = s;
                bdw[(size_t)b * BCAP + p]  = make_uint2((unsigned)d, __float_as_uint(wv));
            }
        }
        return;
    }

    // ---------------- gemm path ----------------
    ushort* blds = (ushort*)smem;
    int gid = blockIdx.x - 256;
    int z   = gid / (2 * nrt);
    int rem = gid - z * (2 * nrt);
    int by  = rem >> 1;
    int bx  = rem & 1;
    int n0  = bx * 128;
    int bm  = by * 128;
    const float* A = z ? A1 : A0;
    int halfoff = z * 256;

    int w = tid >> 6, l = tid & 63;
    int lr = l & 15, lk = l >> 4;

    int r0 = bm + w * 32 + lr;
    int r1 = r0 + 16;
    int rc0 = min(r0, M - 1), rc1 = min(r1, M - 1);

    f4v acc[2][8];
    #pragma unroll
    for (int m = 0; m < 2; ++m)
        #pragma unroll
        for (int t = 0; t < 8; ++t)
            acc[m][t] = (f4v){0.f, 0.f, 0.f, 0.f};

    for (int kp = 0; kp < 2; ++kp){
        #pragma unroll
        for (int j = 0; j < 8; ++j){
            int c  = j * 256 + tid;
            int nl = c >> 4, kc = c & 15;
            uint4 v = *reinterpret_cast<const uint4*>(
                Bt + (((size_t)(n0 + nl)) << 8) + kp * 128 + (kc << 3));
            unsigned boff = (unsigned)(((nl << 8) + (kc << 4)) ^ ((nl & 7) << 4));
            *reinterpret_cast<uint4*>(reinterpret_cast<char*>(blds) + boff) = v;
        }

        const float* a0 = A + (size_t)rc0 * 256 + kp * 128 + lk * 8;
        const float* a1 = A + (size_t)rc1 * 256 + kp * 128 + lk * 8;
        s8v af0[4], af1[4];
        #pragma unroll
        for (int ks = 0; ks < 4; ++ks){
            float4 x0 = *reinterpret_cast<const float4*>(a0 + ks * 32);
            float4 x1 = *reinterpret_cast<const float4*>(a0 + ks * 32 + 4);
            af0[ks][0] = (short)f2bf(x0.x); af0[ks][1] = (short)f2bf(x0.y);
            af0[ks][2] = (short)f2bf(x0.z); af0[ks][3] = (short)f2bf(x0.w);
            af0[ks][4] = (short)f2bf(x1.x); af0[ks][5] = (short)f2bf(x1.y);
            af0[ks][6] = (short)f2bf(x1.z); af0[ks][7] = (short)f2bf(x1.w);
            float4 y0 = *reinterpret_cast<const float4*>(a1 + ks * 32);
            float4 y1 = *reinterpret_cast<const float4*>(a1 + ks * 32 + 4);
            af1[ks][0] = (short)f2bf(y0.x); af1[ks][1] = (short)f2bf(y0.y);
            af1[ks][2] = (short)f2bf(y0.z); af1[ks][3] = (short)f2bf(y0.w);
            af1[ks][4] = (short)f2bf(y1.x); af1[ks][5] = (short)f2bf(y1.y);
            af1[ks][6] = (short)f2bf(y1.z); af1[ks][7] = (short)f2bf(y1.w);
        }
        __syncthreads();

        #pragma unroll
        for (int ks = 0; ks < 4; ++ks){
            #pragma unroll
            for (int t = 0; t < 8; ++t){
                int nl = t * 16 + lr;
                unsigned boff = (unsigned)(((nl << 8) + ((ks * 4 + lk) << 4)) ^ ((nl & 7) << 4));
                s8v bf = *reinterpret_cast<const s8v*>(reinterpret_cast<const char*>(blds) + boff);
                acc[0][t] = __builtin_amdgcn_mfma_f32_16x16x32_bf16(af0[ks], bf, acc[0][t], 0, 0, 0);
                acc[1][t] = __builtin_amdgcn_mfma_f32_16x16x32_bf16(af1[ks], bf, acc[1][t], 0, 0, 0);
            }
        }
        if (kp == 0) __syncthreads();
    }

    #pragma unroll
    for (int m = 0; m < 2; ++m){
        #pragma unroll
        for (int t = 0; t < 8; ++t){
            int col = n0 + t * 16 + lr;
            #pragma unroll
            for (int j = 0; j < 4; ++j){
                int row = bm + w * 32 + m * 16 + lk * 4 + j;
                if (row < M) C8[(size_t)row * 512 + halfoff + col] = f2fp8(acc[m][t][j]);
            }
        }
    }
}

// ---------------- per-bucket CSR build with inline bucket-base scan ----------
__global__ __launch_bounds__(256) void csr_build_kernel(
        const int* __restrict__ bcnt,
        const int* __restrict__ bsrc, const uint2* __restrict__ bdw,
        int* __restrict__ roff, uint2* __restrict__ csr, int n, int nbuck){
    __shared__ int sb[256];
    __shared__ int hist[256];
    __shared__ int loc[256];
    __shared__ int cur[256];
    int b = blockIdx.x, t = threadIdx.x;

    // inline bucket-base: inclusive scan of clamped bucket counts
    int vb = (t < nbuck) ? min(bcnt[t * 32], BCAP) : 0;
    sb[t] = vb;
    __syncthreads();
    for (int off = 1; off < 256; off <<= 1){
        int x = (t >= off) ? sb[t - off] : 0;
        __syncthreads();
        sb[t] += x;
        __syncthreads();
    }
    if (b == 0 && t == 0) roff[n] = sb[nbuck - 1];   // total = E
    int cnt  = min(bcnt[b * 32], BCAP);
    int base = sb[b] - cnt;                           // exclusive prefix at b
    __syncthreads();

    hist[t] = 0;
    __syncthreads();
    for (int i = t; i < cnt; i += 256)
        atomicAdd(&hist[bsrc[(size_t)b * BCAP + i] & 255], 1);
    __syncthreads();
    int v = hist[t];
    loc[t] = v;
    __syncthreads();
    for (int off = 1; off < 256; off <<= 1){
        int x = (t >= off) ? loc[t - off] : 0;
        __syncthreads();
        loc[t] += x;
        __syncthreads();
    }
    int gi = b * 256 + t;
    if (gi < n) roff[gi] = base + loc[t] - v;
    cur[t] = 0;
    __syncthreads();
    for (int i = t; i < cnt; i += 256){
        int s   = bsrc[(size_t)b * BCAP + i];
        int idx = s & 255;
        int p = base + (loc[idx] - hist[idx]) + atomicAdd(&cur[idx], 1);
        csr[p] = bdw[(size_t)b * BCAP + i];
    }
}

// ---------------- fused SPMM over H=256 (student+teacher), fp8 table, + bias + selu ----
__global__ __launch_bounds__(256) void spmm_h2_kernel(
        const unsigned char* __restrict__ XWp,
        const int* __restrict__ roff, const uint2* __restrict__ csr,
        const float* __restrict__ b1,
        ushort* __restrict__ Gs, ushort* __restrict__ Gt, int n){
    int wid = threadIdx.x >> 6, lane = threadIdx.x & 63;
    int r = blockIdx.x * 4 + wid;
    if (r >= n) return;
    int half = lane >> 5;          // 0 = student, 1 = teacher
    int hl   = lane & 31;          // col group: cols hl*8 .. hl*8+7
    const unsigned char* base = XWp + lane * 8;
    int e0 = roff[r], e1 = roff[r + 1];
    float acc[8] = {};

    #define ACCUM8(V, W) do{                                                      \
        auto fa_ = __builtin_amdgcn_cvt_pk_f32_fp8((V).x, false);                 \
        acc[0] = fmaf((W), fa_[0], acc[0]); acc[1] = fmaf((W), fa_[1], acc[1]);   \
        auto fb_ = __builtin_amdgcn_cvt_pk_f32_fp8((V).x, true);                  \
        acc[2] = fmaf((W), fb_[0], acc[2]); acc[3] = fmaf((W), fb_[1], acc[3]);   \
        auto fc_ = __builtin_amdgcn_cvt_pk_f32_fp8((V).y, false);                 \
        acc[4] = fmaf((W), fc_[0], acc[4]); acc[5] = fmaf((W), fc_[1], acc[5]);   \
        auto fd_ = __builtin_amdgcn_cvt_pk_f32_fp8((V).y, true);                  \
        acc[6] = fmaf((W), fd_[0], acc[6]); acc[7] = fmaf((W), fd_[1], acc[7]);   \
    }while(0)

    int e = e0;
    for (; e + 7 < e1; e += 8){
        uint2 c0 = csr[e],     c1 = csr[e + 1];
        uint2 c2 = csr[e + 2], c3 = csr[e + 3];
        uint2 c4 = csr[e + 4], c5 = csr[e + 5];
        uint2 c6 = csr[e + 6], c7 = csr[e + 7];
        uint2 v0 = *reinterpret_cast<const uint2*>(base + ((size_t)c0.x << 9));
        uint2 v1 = *reinterpret_cast<const uint2*>(base + ((size_t)c1.x << 9));
        uint2 v2 = *reinterpret_cast<const uint2*>(base + ((size_t)c2.x << 9));
        uint2 v3 = *reinterpret_cast<const uint2*>(base + ((size_t)c3.x << 9));
        uint2 v4 = *reinterpret_cast<const uint2*>(base + ((size_t)c4.x << 9));
        uint2 v5 = *reinterpret_cast<const uint2*>(base + ((size_t)c5.x << 9));
        uint2 v6 = *reinterpret_cast<const uint2*>(base + ((size_t)c6.x << 9));
        uint2 v7 = *reinterpret_cast<const uint2*>(base + ((size_t)c7.x << 9));
        ACCUM8(v0, __uint_as_float(c0.y)); ACCUM8(v1, __uint_as_float(c1.y));
        ACCUM8(v2, __uint_as_float(c2.y)); ACCUM8(v3, __uint_as_float(c3.y));
        ACCUM8(v4, __uint_as_float(c4.y)); ACCUM8(v5, __uint_as_float(c5.y));
        ACCUM8(v6, __uint_as_float(c6.y)); ACCUM8(v7, __uint_as_float(c7.y));
    }
    for (; e + 3 < e1; e += 4){
        uint2 c0 = csr[e],     c1 = csr[e + 1];
        uint2 c2 = csr[e + 2], c3 = csr[e + 3];
        uint2 v0 = *reinterpret_cast<const uint2*>(base + ((size_t)c0.x << 9));
        uint2 v1 = *reinterpret_cast<const uint2*>(base + ((size_t)c1.x << 9));
        uint2 v2 = *reinterpret_cast<const uint2*>(base + ((size_t)c2.x << 9));
        uint2 v3 = *reinterpret_cast<const uint2*>(base + ((size_t)c3.x << 9));
        ACCUM8(v0, __uint_as_float(c0.y)); ACCUM8(v1, __uint_as_float(c1.y));
        ACCUM8(v2, __uint_as_float(c2.y)); ACCUM8(v3, __uint_as_float(c3.y));
    }
    for (; e < e1; ++e){
        uint2 c = csr[e];
        uint2 v = *reinterpret_cast<const uint2*>(base + ((size_t)c.x << 9));
        ACCUM8(v, __uint_as_float(c.y));
    }
    #undef ACCUM8

    const float* bp = b1 + hl * 8;
    float4 bb0 = *reinterpret_cast<const float4*>(bp);
    float4 bb1 = *reinterpret_cast<const float4*>(bp + 4);
    float bv[8] = {bb0.x, bb0.y, bb0.z, bb0.w, bb1.x, bb1.y, bb1.z, bb1.w};
    ushort o[8];
    #pragma unroll
    for (int q = 0; q < 8; ++q) o[q] = f2bf(selu1(acc[q] + bv[q]));
    uint4 ov = *reinterpret_cast<const uint4*>(o);
    ushort* gout = (half ? Gt : Gs) + (size_t)r * Hdim + hl * 8;
    *reinterpret_cast<uint4*>(gout) = ov;
}

// ---------------- fused MFMA: GS = pack(Gs@Ws, Gt@Wt) bf16   [N,256]x[256,16] ----------
__global__ __launch_bounds__(256) void gemm_k2_kernel(
        const ushort* __restrict__ Gs, const ushort* __restrict__ Gt,
        const ushort* __restrict__ WsT, const ushort* __restrict__ WtT,
        unsigned* __restrict__ GSp, int n){
    int wv = blockIdx.x * 4 + (threadIdx.x >> 6);
    int l  = threadIdx.x & 63;
    int lr = l & 15, lk = l >> 4;
    int nw = (n + 15) >> 4;
    if (wv >= nw) return;
    int r0 = wv * 16;

    s8v bs_[8], bt_[8];
    #pragma unroll
    for (int ks = 0; ks < 8; ++ks){
        bs_[ks] = *reinterpret_cast<const s8v*>(WsT + lr * 256 + ks * 32 + lk * 8);
        bt_[ks] = *reinterpret_cast<const s8v*>(WtT + lr * 256 + ks * 32 + lk * 8);
    }

    f4v accs = (f4v){0.f,0.f,0.f,0.f}, acct = (f4v){0.f,0.f,0.f,0.f};
    int row = min(r0 + lr, n - 1);
    const ushort* gsrow = Gs + (size_t)row * 256 + lk * 8;
    const ushort* gtrow = Gt + (size_t)row * 256 + lk * 8;
    #pragma unroll
    for (int ks = 0; ks < 8; ++ks){
        s8v a_s = *reinterpret_cast<const s8v*>(gsrow + ks * 32);
        s8v a_t = *reinterpret_cast<const s8v*>(gtrow + ks * 32);
        accs = __builtin_amdgcn_mfma_f32_16x16x32_bf16(a_s, bs_[ks], accs, 0, 0, 0);
        acct = __builtin_amdgcn_mfma_f32_16x16x32_bf16(a_t, bt_[ks], acct, 0, 0, 0);
    }
    #pragma unroll
    for (int j = 0; j < 4; ++j){
        int rr = r0 + lk * 4 + j;
        if (rr < n){
            unsigned pv = (unsigned)f2bf(accs[j]) | ((unsigned)f2bf(acct[j]) << 16);
            GSp[(size_t)rr * 16 + lr] = pv;
        }
    }
}

// ---------------- fused: SPMM-K + softmax (both branches) + cluster/con stats --------
__global__ __launch_bounds__(256) void spmm_k2_kernel(
        const unsigned* __restrict__ GSp,
        const int* __restrict__ roff, const uint2* __restrict__ csr,
        const float* __restrict__ bsv, const float* __restrict__ btv,
        float* __restrict__ asg, float* __restrict__ red, int n){
    int tid  = threadIdx.x;
    int wid  = tid >> 6, lane = tid & 63;
    int slot = lane >> 4, j = lane & 15;
    float bs_ = bsv[j], bt_ = btv[j];
    float cs_l = 0.f, con_l = 0.f;

    int rstride = gridDim.x * 4;
    for (int r = blockIdx.x * 4 + wid; r < n; r += rstride){
        int e0 = roff[r], e1 = roff[r + 1];
        float as_ = 0.f, at_ = 0.f;
        for (int e = e0 + slot; e < e1; e += 4){
            uint2 c = csr[e];
            float w = __uint_as_float(c.y);
            unsigned v = GSp[(size_t)c.x * 16 + j];
            as_ = fmaf(w, bflo(v), as_);
            at_ = fmaf(w, bfhi(v), at_);
        }
        as_ += __shfl_xor(as_, 16); as_ += __shfl_xor(as_, 32);
        at_ += __shfl_xor(at_, 16); at_ += __shfl_xor(at_, 32);
        float xs = selu1(as_ + bs_);
        float xt = selu1(at_ + bt_);
        float ms = xs, mt = xt;
        #pragma unroll
        for (int off = 8; off >= 1; off >>= 1){
            ms = fmaxf(ms, __shfl_xor(ms, off));
            mt = fmaxf(mt, __shfl_xor(mt, off));
        }
        float es = expf(xs - ms), et = expf(xt - mt);
        float ss = es, st = et;
        #pragma unroll
        for (int off = 8; off >= 1; off >>= 1){
            ss += __shfl_xor(ss, off);
            st += __shfl_xor(st, off);
        }
        float a = es / ss, b = et / st;
        if (slot == 0) asg[(size_t)r * 16 + j] = a;
        cs_l += a;
        float dot = a * b, na = a * a, nb = b * b;
        #pragma unroll
        for (int off = 8; off >= 1; off >>= 1){
            dot += __shfl_xor(dot, off);
            na  += __shfl_xor(na, off);
            nb  += __shfl_xor(nb, off);
        }
        if (j == 0){
            na = fmaxf(sqrtf(na), 1e-12f);
            nb = fmaxf(sqrtf(nb), 1e-12f);
            con_l += 2.f - 2.f * dot / (na * nb);
        }
    }

    // slots hold exact duplicates -> combine then scale by 1/4
    cs_l  += __shfl_xor(cs_l, 16);  cs_l  += __shfl_xor(cs_l, 32);  cs_l  *= 0.25f;
    con_l += __shfl_xor(con_l, 16); con_l += __shfl_xor(con_l, 32); con_l *= 0.25f;

    __shared__ float part[4][17];
    if (lane < 16) part[wid][lane] = cs_l;
    if (lane == 0) part[wid][16]   = con_l;
    __syncthreads();
    if (tid < 16){
        float s = part[0][tid] + part[1][tid] + part[2][tid] + part[3][tid];
        atomicAdd(&red[(16 + tid) * RSTRIDE], s);
    } else if (tid == 16){
        float s = part[0][16] + part[1][16] + part[2][16] + part[3][16];
        atomicAdd(&red[32 * RSTRIDE], s);
    }
}

// ---------------- per-edge: trace + nl[k] = sum_e S[dst_e][k] ----------------
__global__ __launch_bounds__(256) void edge_trace_kernel(const int* __restrict__ src,
        const int* __restrict__ dst, const float* __restrict__ as_,
        float* __restrict__ red, int E){
    int tid    = blockIdx.x * blockDim.x + threadIdx.x;
    int stride = gridDim.x * blockDim.x;
    float dot = 0.f;
    float nl[16] = {};
    for (int i = tid; i < E; i += stride){
        const float4* pa = reinterpret_cast<const float4*>(as_ + (size_t)src[i] * 16);
        const float4* pb = reinterpret_cast<const float4*>(as_ + (size_t)dst[i] * 16);
        #pragma unroll
        for (int q = 0; q < 4; ++q){
            float4 va = pa[q]; float4 vb = pb[q];
            dot = fmaf(va.x, vb.x, dot); dot = fmaf(va.y, vb.y, dot);
            dot = fmaf(va.z, vb.z, dot); dot = fmaf(va.w, vb.w, dot);
            nl[q*4+0] += vb.x; nl[q*4+1] += vb.y;
            nl[q*4+2] += vb.z; nl[q*4+3] += vb.w;
        }
    }
    #pragma unroll
    for (int off = 1; off < 64; off <<= 1){
        dot += __shfl_xor(dot, off);
        #pragma unroll
        for (int k = 0; k < 16; ++k) nl[k] += __shfl_xor(nl[k], off);
    }
    __shared__ float part[4][17];
    int wid = threadIdx.x >> 6, lane = threadIdx.x & 63;
    if (lane == 0){
        #pragma unroll
        for (int k = 0; k < 16; ++k) part[wid][k] = nl[k];
        part[wid][16] = dot;
    }
    __syncthreads();
    int t = threadIdx.x;
    if (t < 16){
        float s = part[0][t] + part[1][t] + part[2][t] + part[3][t];
        atomicAdd(&red[t * RSTRIDE], s);
    } else if (t == 16){
        float s = part[0][16] + part[1][16] + part[2][16] + part[3][16];
        atomicAdd(&red[33 * RSTRIDE], s);
    }
}

// ---------------- finalize ----------------
__global__ void finalize_kernel(const float* __restrict__ red, float* __restrict__ out,
                                int n, int E){
    float trace = red[33 * RSTRIDE];
    float nl2 = 0.f, cs2 = 0.f;
    #pragma unroll
    for (int k = 0; k < 16; ++k){
        nl2 = fmaf(red[k * RSTRIDE],        red[k * RSTRIDE],        nl2);
        cs2 = fmaf(red[(16 + k) * RSTRIDE], red[(16 + k) * RSTRIDE], cs2);
    }
    float twoE = 2.f * (float)E;
    float spectral = -(trace - nl2 / twoE) / twoE;
    float cluster  = sqrtf(cs2) / (float)n * 4.f - 1.f;
    float con      = red[32 * RSTRIDE] / (float)n;
    out[0] = spectral + cluster + con;
}

extern "C" void kernel_launch(void* const* d_in, const int* in_sizes, int n_in,
                              void* d_out, int out_size, void* d_ws, size_t ws_size,
                              hipStream_t stream){
    const int*   esrc = (const int*)d_in[0];
    const int*   edst = (const int*)d_in[1];
    const float* ew   = (const float*)d_in[2];
    const float* feat = (const float*)d_in[3];
    const float* faug = (const float*)d_in[4];
    const float* W1   = (const float*)d_in[5];
    const float* b1   = (const float*)d_in[6];
    const float* Wsm  = (const float*)d_in[7];
    const float* bsv  = (const float*)d_in[8];
    const float* Wtm  = (const float*)d_in[9];
    const float* btv  = (const float*)d_in[10];
    int E = in_sizes[0];
    int N = in_sizes[3] / Fdim;

    char* ws = (char*)d_ws;
    size_t off = 0;
    auto alloc = [&](size_t bytes) -> char* {
        char* p = ws + off;
        off = (off + bytes + 255) & ~(size_t)255;
        return p;
    };
    int nbuck = (N + 255) >> 8;
    unsigned char* XWp = (unsigned char*)alloc((size_t)N * 512);  // fp8 [N][512B]
    ushort*   Gs    = (ushort*)alloc((size_t)N * Hdim * 2);
    ushort*   Gt    = (ushort*)alloc((size_t)N * Hdim * 2);
    unsigned* GSp   = (unsigned*)alloc((size_t)N * Kc * 4);
    float*    ASG_S = (float*)alloc((size_t)N * Kc * 4);
    ushort*   WT    = (ushort*)alloc((size_t)256 * 256 * 2);
    ushort*   WsT   = (ushort*)alloc((size_t)16 * 256 * 2);
    ushort*   WtT   = (ushort*)alloc((size_t)16 * 256 * 2);
    int*      ROFF  = (int*)alloc((size_t)(N + 1) * 4);
    int*      BCNT  = (int*)alloc((size_t)nbuck * 32 * 4);
    int*      BSRC  = (int*)alloc((size_t)nbuck * BCAP * 4);
    uint2*    BDW   = (uint2*)alloc((size_t)nbuck * BCAP * 8);
    uint2*    CSR8  = (uint2*)alloc((size_t)E * 8);
    float*    RED   = (float*)alloc((size_t)NRED * RSTRIDE * 4);

    hipMemsetAsync(BCNT, 0, (size_t)nbuck * 32 * 4, stream);
    hipMemsetAsync(RED, 0, (size_t)NRED * RSTRIDE * 4, stream);

    prep_kernel<<<257, 256, 0, stream>>>(W1, WT, Wsm, Wtm, WsT, WtT);

    int nrt = (N + 127) / 128;
    int mega_blocks = 256 + 2 * nrt * 2;
    mega_kernel<<<mega_blocks, 256, 0, stream>>>(esrc, edst, ew, BCNT, BSRC, BDW,
                                                 E, nbuck, feat, faug, WT, XWp,
                                                 N, nrt);

    csr_build_kernel<<<nbuck, 256, 0, stream>>>(BCNT, BSRC, BDW, CSR8 ? ROFF : ROFF,
                                                CSR8, N, nbuck);

    spmm_h2_kernel<<<(N + 3) / 4, 256, 0, stream>>>(XWp, ROFF, CSR8, b1, Gs, Gt, N);

    int nw = (N + 15) / 16;
    gemm_k2_kernel<<<(nw + 3) / 4, 256, 0, stream>>>(Gs, Gt, WsT, WtT, GSp, N);

    spmm_k2_kernel<<<2048, 256, 0, stream>>>(GSp, ROFF, CSR8, bsv, btv,
                                             ASG_S, RED, N);

    edge_trace_kernel<<<256, 256, 0, stream>>>(esrc, edst, ASG_S, RED, E);
    finalize_kernel<<<1, 1, 0, stream>>>(RED, (float*)d_out, N, E);
}

// Round 18
// 225.149 us; speedup vs baseline: 1.5405x; 1.0507x over previous
//
#include <hip/hip_runtime.h>
#include <math.h>

constexpr int Fdim = 256;
constexpr int Hdim = 256;
constexpr int Kc   = 16;

constexpr int RSTRIDE = 32;
constexpr int NRED    = 34;   // 0..15 nl, 16..31 cluster_sizes, 32 con, 33 trace
constexpr int BCAP    = 5120; // bucket capacity (mean 4096, 16 sigma slack)

typedef __attribute__((ext_vector_type(8))) short s8v;   // 8 bf16 (4 VGPRs)
typedef __attribute__((ext_vector_type(4))) float f4v;   // 4 fp32 acc

__device__ __forceinline__ float selu1(float x){
    const float scale = 1.0507009873554805f;
    const float alpha = 1.6732632423543772f;
    return scale * (x > 0.f ? x : alpha * expm1f(x));
}

__device__ __forceinline__ ushort f2bf(float x){
    union { float f; unsigned u; } c; c.f = x;
    unsigned r = c.u + 0x7fffu + ((c.u >> 16) & 1u);   // RNE
    return (ushort)(r >> 16);
}

__device__ __forceinline__ float bflo(unsigned v){
    union { unsigned u; float f; } c; c.u = v << 16; return c.f;
}
__device__ __forceinline__ float bfhi(unsigned v){
    union { unsigned u; float f; } c; c.u = v & 0xffff0000u; return c.f;
}

// fp8 e4m3 encode via HW converter (RNE)
__device__ __forceinline__ unsigned char f2fp8(float x){
    int v = __builtin_amdgcn_cvt_pk_fp8_f32(x, x, 0, false);
    return (unsigned char)(v & 0xff);
}

// ---------------- prep: castw (0..255) + castwk/zeroRED (256) + zeroBCNT (257) ------
__global__ __launch_bounds__(256) void prep_kernel(
        const float* __restrict__ W1, ushort* __restrict__ WT,
        const float* __restrict__ Ws, const float* __restrict__ Wt,
        ushort* __restrict__ WsT, ushort* __restrict__ WtT,
        float* __restrict__ red, int* __restrict__ bcnt, int nbuck){
    __shared__ float tbuf[16][17];
    int b = blockIdx.x;
    int t = threadIdx.x;
    if (b < 256){
        int bx = b & 15, by = b >> 4;
        int tx = t & 15, ty = t >> 4;
        int k  = by * 16 + ty;
        int nn = bx * 16 + tx;
        tbuf[ty][tx] = W1[k * 256 + nn];
        __syncthreads();
        int n2 = bx * 16 + ty;
        int k2 = by * 16 + tx;
        WT[n2 * 256 + k2] = f2bf(tbuf[tx][ty]);
    } else if (b == 256){
        int h = t;
        #pragma unroll
        for (int c = 0; c < 16; ++c){
            WsT[c * 256 + h] = f2bf(Ws[h * 16 + c]);
            WtT[c * 256 + h] = f2bf(Wt[h * 16 + c]);
        }
        for (int i = t; i < NRED * RSTRIDE; i += 256) red[i] = 0.f;
    } else {
        for (int i = t; i < nbuck * 32; i += 256) bcnt[i] = 0;
    }
}

// ---------------- MEGA: bin (blocks 0..255) + MFMA GEMM (blocks 256..) ----------
__global__ __launch_bounds__(256, 2) void mega_kernel(
        const int* __restrict__ esrc, const int* __restrict__ edst,
        const float* __restrict__ ew, int* __restrict__ bcnt,
        int* __restrict__ bsrc, uint2* __restrict__ bdw, int E, int nbuck,
        const float* __restrict__ A0, const float* __restrict__ A1,
        const ushort* __restrict__ Bt, unsigned char* __restrict__ C8,
        int M, int nrt){
    __shared__ char smem[32768];
    int tid = threadIdx.x;

    if (blockIdx.x < 256){
        // ---------------- bin path ----------------
        int* hist = (int*)smem;
        int* base = hist + 256;
        int* cur  = base + 256;
        int chunk = (E + 255) / 256;
        int lo = blockIdx.x * chunk;
        int hi = min(lo + chunk, E);
        hist[tid] = 0;
        __syncthreads();
        for (int i = lo + tid; i < hi; i += 256)
            atomicAdd(&hist[esrc[i] >> 8], 1);
        __syncthreads();
        if (tid < nbuck && hist[tid] > 0)
            base[tid] = atomicAdd(&bcnt[tid * 32], hist[tid]);
        cur[tid] = 0;
        __syncthreads();
        for (int i = lo + tid; i < hi; i += 256){
            int s = esrc[i], d = edst[i];
            float wv = ew[i];
            int b = s >> 8;
            int p = base[b] + atomicAdd(&cur[b], 1);
            if (p < BCAP){
                bsrc[(size_t)b * BCAP + p] = s;
                bdw[(size_t)b * BCAP + p]  = make_uint2((unsigned)d, __float_as_uint(wv));
            }
        }
        return;
    }

    // ---------------- gemm path ----------------
    ushort* blds = (ushort*)smem;
    int gid = blockIdx.x - 256;
    int z   = gid / (2 * nrt);
    int rem = gid - z * (2 * nrt);
    int by  = rem >> 1;
    int bx  = rem & 1;
    int n0  = bx * 128;
    int bm  = by * 128;
    const float* A = z ? A1 : A0;
    int halfoff = z * 256;

    int w = tid >> 6, l = tid & 63;
    int lr = l & 15, lk = l >> 4;

    int r0 = bm + w * 32 + lr;
    int r1 = r0 + 16;
    int rc0 = min(r0, M - 1), rc1 = min(r1, M - 1);

    f4v acc[2][8];
    #pragma unroll
    for (int m = 0; m < 2; ++m)
        #pragma unroll
        for (int t = 0; t < 8; ++t)
            acc[m][t] = (f4v){0.f, 0.f, 0.f, 0.f};

    for (int kp = 0; kp < 2; ++kp){
        #pragma unroll
        for (int j = 0; j < 8; ++j){
            int c  = j * 256 + tid;
            int nl = c >> 4, kc = c & 15;
            uint4 v = *reinterpret_cast<const uint4*>(
                Bt + (((size_t)(n0 + nl)) << 8) + kp * 128 + (kc << 3));
            unsigned boff = (unsigned)(((nl << 8) + (kc << 4)) ^ ((nl & 7) << 4));
            *reinterpret_cast<uint4*>(reinterpret_cast<char*>(blds) + boff) = v;
        }

        const float* a0 = A + (size_t)rc0 * 256 + kp * 128 + lk * 8;
        const float* a1 = A + (size_t)rc1 * 256 + kp * 128 + lk * 8;
        s8v af0[4], af1[4];
        #pragma unroll
        for (int ks = 0; ks < 4; ++ks){
            float4 x0 = *reinterpret_cast<const float4*>(a0 + ks * 32);
            float4 x1 = *reinterpret_cast<const float4*>(a0 + ks * 32 + 4);
            af0[ks][0] = (short)f2bf(x0.x); af0[ks][1] = (short)f2bf(x0.y);
            af0[ks][2] = (short)f2bf(x0.z); af0[ks][3] = (short)f2bf(x0.w);
            af0[ks][4] = (short)f2bf(x1.x); af0[ks][5] = (short)f2bf(x1.y);
            af0[ks][6] = (short)f2bf(x1.z); af0[ks][7] = (short)f2bf(x1.w);
            float4 y0 = *reinterpret_cast<const float4*>(a1 + ks * 32);
            float4 y1 = *reinterpret_cast<const float4*>(a1 + ks * 32 + 4);
            af1[ks][0] = (short)f2bf(y0.x); af1[ks][1] = (short)f2bf(y0.y);
            af1[ks][2] = (short)f2bf(y0.z); af1[ks][3] = (short)f2bf(y0.w);
            af1[ks][4] = (short)f2bf(y1.x); af1[ks][5] = (short)f2bf(y1.y);
            af1[ks][6] = (short)f2bf(y1.z); af1[ks][7] = (short)f2bf(y1.w);
        }
        __syncthreads();

        #pragma unroll
        for (int ks = 0; ks < 4; ++ks){
            #pragma unroll
            for (int t = 0; t < 8; ++t){
                int nl = t * 16 + lr;
                unsigned boff = (unsigned)(((nl << 8) + ((ks * 4 + lk) << 4)) ^ ((nl & 7) << 4));
                s8v bf = *reinterpret_cast<const s8v*>(reinterpret_cast<const char*>(blds) + boff);
                acc[0][t] = __builtin_amdgcn_mfma_f32_16x16x32_bf16(af0[ks], bf, acc[0][t], 0, 0, 0);
                acc[1][t] = __builtin_amdgcn_mfma_f32_16x16x32_bf16(af1[ks], bf, acc[1][t], 0, 0, 0);
            }
        }
        if (kp == 0) __syncthreads();
    }

    #pragma unroll
    for (int m = 0; m < 2; ++m){
        #pragma unroll
        for (int t = 0; t < 8; ++t){
            int col = n0 + t * 16 + lr;
            #pragma unroll
            for (int j = 0; j < 4; ++j){
                int row = bm + w * 32 + m * 16 + lk * 4 + j;
                if (row < M) C8[(size_t)row * 512 + halfoff + col] = f2fp8(acc[m][t][j]);
            }
        }
    }
}

// ---------------- per-bucket CSR build with inline bucket-base scan ----------
__global__ __launch_bounds__(256) void csr_build_kernel(
        const int* __restrict__ bcnt,
        const int* __restrict__ bsrc, const uint2* __restrict__ bdw,
        int* __restrict__ roff, uint2* __restrict__ csr, int n, int nbuck){
    __shared__ int sb[256];
    __shared__ int hist[256];
    __shared__ int loc[256];
    __shared__ int cur[256];
    int b = blockIdx.x, t = threadIdx.x;

    int vb = (t < nbuck) ? min(bcnt[t * 32], BCAP) : 0;
    sb[t] = vb;
    __syncthreads();
    for (int off = 1; off < 256; off <<= 1){
        int x = (t >= off) ? sb[t - off] : 0;
        __syncthreads();
        sb[t] += x;
        __syncthreads();
    }
    if (b == 0 && t == 0) roff[n] = sb[nbuck - 1];
    int cnt  = min(bcnt[b * 32], BCAP);
    int base = sb[b] - cnt;
    __syncthreads();

    hist[t] = 0;
    __syncthreads();
    for (int i = t; i < cnt; i += 256)
        atomicAdd(&hist[bsrc[(size_t)b * BCAP + i] & 255], 1);
    __syncthreads();
    int v = hist[t];
    loc[t] = v;
    __syncthreads();
    for (int off = 1; off < 256; off <<= 1){
        int x = (t >= off) ? loc[t - off] : 0;
        __syncthreads();
        loc[t] += x;
        __syncthreads();
    }
    int gi = b * 256 + t;
    if (gi < n) roff[gi] = base + loc[t] - v;
    cur[t] = 0;
    __syncthreads();
    for (int i = t; i < cnt; i += 256){
        int s   = bsrc[(size_t)b * BCAP + i];
        int idx = s & 255;
        int p = base + (loc[idx] - hist[idx]) + atomicAdd(&cur[idx], 1);
        csr[p] = bdw[(size_t)b * BCAP + i];
    }
}

// ---------------- fused SPMM over H=256 (student+teacher), fp8 table, + bias + selu ----
__global__ __launch_bounds__(256) void spmm_h2_kernel(
        const unsigned char* __restrict__ XWp,
        const int* __restrict__ roff, const uint2* __restrict__ csr,
        const float* __restrict__ b1,
        ushort* __restrict__ Gs, ushort* __restrict__ Gt, int n){
    int wid = threadIdx.x >> 6, lane = threadIdx.x & 63;
    int r = blockIdx.x * 4 + wid;
    if (r >= n) return;
    int half = lane >> 5;          // 0 = student, 1 = teacher
    int hl   = lane & 31;          // col group: cols hl*8 .. hl*8+7
    const unsigned char* base = XWp + lane * 8;
    int e0 = roff[r], e1 = roff[r + 1];
    float acc[8] = {};

    #define ACCUM8(V, W) do{                                                      \
        auto fa_ = __builtin_amdgcn_cvt_pk_f32_fp8((V).x, false);                 \
        acc[0] = fmaf((W), fa_[0], acc[0]); acc[1] = fmaf((W), fa_[1], acc[1]);   \
        auto fb_ = __builtin_amdgcn_cvt_pk_f32_fp8((V).x, true);                  \
        acc[2] = fmaf((W), fb_[0], acc[2]); acc[3] = fmaf((W), fb_[1], acc[3]);   \
        auto fc_ = __builtin_amdgcn_cvt_pk_f32_fp8((V).y, false);                 \
        acc[4] = fmaf((W), fc_[0], acc[4]); acc[5] = fmaf((W), fc_[1], acc[5]);   \
        auto fd_ = __builtin_amdgcn_cvt_pk_f32_fp8((V).y, true);                  \
        acc[6] = fmaf((W), fd_[0], acc[6]); acc[7] = fmaf((W), fd_[1], acc[7]);   \
    }while(0)

    int e = e0;
    for (; e + 7 < e1; e += 8){
        uint2 c0 = csr[e],     c1 = csr[e + 1];
        uint2 c2 = csr[e + 2], c3 = csr[e + 3];
        uint2 c4 = csr[e + 4], c5 = csr[e + 5];
        uint2 c6 = csr[e + 6], c7 = csr[e + 7];
        uint2 v0 = *reinterpret_cast<const uint2*>(base + ((size_t)c0.x << 9));
        uint2 v1 = *reinterpret_cast<const uint2*>(base + ((size_t)c1.x << 9));
        uint2 v2 = *reinterpret_cast<const uint2*>(base + ((size_t)c2.x << 9));
        uint2 v3 = *reinterpret_cast<const uint2*>(base + ((size_t)c3.x << 9));
        uint2 v4 = *reinterpret_cast<const uint2*>(base + ((size_t)c4.x << 9));
        uint2 v5 = *reinterpret_cast<const uint2*>(base + ((size_t)c5.x << 9));
        uint2 v6 = *reinterpret_cast<const uint2*>(base + ((size_t)c6.x << 9));
        uint2 v7 = *reinterpret_cast<const uint2*>(base + ((size_t)c7.x << 9));
        ACCUM8(v0, __uint_as_float(c0.y)); ACCUM8(v1, __uint_as_float(c1.y));
        ACCUM8(v2, __uint_as_float(c2.y)); ACCUM8(v3, __uint_as_float(c3.y));
        ACCUM8(v4, __uint_as_float(c4.y)); ACCUM8(v5, __uint_as_float(c5.y));
        ACCUM8(v6, __uint_as_float(c6.y)); ACCUM8(v7, __uint_as_float(c7.y));
    }
    for (; e + 3 < e1; e += 4){
        uint2 c0 = csr[e],     c1 = csr[e + 1];
        uint2 c2 = csr[e + 2], c3 = csr[e + 3];
        uint2 v0 = *reinterpret_cast<const uint2*>(base + ((size_t)c0.x << 9));
        uint2 v1 = *reinterpret_cast<const uint2*>(base + ((size_t)c1.x << 9));
        uint2 v2 = *reinterpret_cast<const uint2*>(base + ((size_t)c2.x << 9));
        uint2 v3 = *reinterpret_cast<const uint2*>(base + ((size_t)c3.x << 9));
        ACCUM8(v0, __uint_as_float(c0.y)); ACCUM8(v1, __uint_as_float(c1.y));
        ACCUM8(v2, __uint_as_float(c2.y)); ACCUM8(v3, __uint_as_float(c3.y));
    }
    for (; e < e1; ++e){
        uint2 c = csr[e];
        uint2 v = *reinterpret_cast<const uint2*>(base + ((size_t)c.x << 9));
        ACCUM8(v, __uint_as_float(c.y));
    }
    #undef ACCUM8

    const float* bp = b1 + hl * 8;
    float4 bb0 = *reinterpret_cast<const float4*>(bp);
    float4 bb1 = *reinterpret_cast<const float4*>(bp + 4);
    float bv[8] = {bb0.x, bb0.y, bb0.z, bb0.w, bb1.x, bb1.y, bb1.z, bb1.w};
    ushort o[8];
    #pragma unroll
    for (int q = 0; q < 8; ++q) o[q] = f2bf(selu1(acc[q] + bv[q]));
    uint4 ov = *reinterpret_cast<const uint4*>(o);
    ushort* gout = (half ? Gt : Gs) + (size_t)r * Hdim + hl * 8;
    *reinterpret_cast<uint4*>(gout) = ov;
}

// ---------------- fused MFMA: GS = pack(Gs@Ws, Gt@Wt) bf16   [N,256]x[256,16] ----------
__global__ __launch_bounds__(256) void gemm_k2_kernel(
        const ushort* __restrict__ Gs, const ushort* __restrict__ Gt,
        const ushort* __restrict__ WsT, const ushort* __restrict__ WtT,
        unsigned* __restrict__ GSp, int n){
    int wv = blockIdx.x * 4 + (threadIdx.x >> 6);
    int l  = threadIdx.x & 63;
    int lr = l & 15, lk = l >> 4;
    int nw = (n + 15) >> 4;
    if (wv >= nw) return;
    int r0 = wv * 16;

    s8v bs_[8], bt_[8];
    #pragma unroll
    for (int ks = 0; ks < 8; ++ks){
        bs_[ks] = *reinterpret_cast<const s8v*>(WsT + lr * 256 + ks * 32 + lk * 8);
        bt_[ks] = *reinterpret_cast<const s8v*>(WtT + lr * 256 + ks * 32 + lk * 8);
    }

    f4v accs = (f4v){0.f,0.f,0.f,0.f}, acct = (f4v){0.f,0.f,0.f,0.f};
    int row = min(r0 + lr, n - 1);
    const ushort* gsrow = Gs + (size_t)row * 256 + lk * 8;
    const ushort* gtrow = Gt + (size_t)row * 256 + lk * 8;
    #pragma unroll
    for (int ks = 0; ks < 8; ++ks){
        s8v a_s = *reinterpret_cast<const s8v*>(gsrow + ks * 32);
        s8v a_t = *reinterpret_cast<const s8v*>(gtrow + ks * 32);
        accs = __builtin_amdgcn_mfma_f32_16x16x32_bf16(a_s, bs_[ks], accs, 0, 0, 0);
        acct = __builtin_amdgcn_mfma_f32_16x16x32_bf16(a_t, bt_[ks], acct, 0, 0, 0);
    }
    #pragma unroll
    for (int j = 0; j < 4; ++j){
        int rr = r0 + lk * 4 + j;
        if (rr < n){
            unsigned pv = (unsigned)f2bf(accs[j]) | ((unsigned)f2bf(acct[j]) << 16);
            GSp[(size_t)rr * 16 + lr] = pv;
        }
    }
}

// ---------------- fused: SPMM-K + softmax + stats; writes packed-bf16 assignments ----
__global__ __launch_bounds__(256) void spmm_k2_kernel(
        const unsigned* __restrict__ GSp,
        const int* __restrict__ roff, const uint2* __restrict__ csr,
        const float* __restrict__ bsv, const float* __restrict__ btv,
        unsigned* __restrict__ asgh, float* __restrict__ red, int n){
    int tid  = threadIdx.x;
    int wid  = tid >> 6, lane = tid & 63;
    int slot = lane >> 4, j = lane & 15;
    float bs_ = bsv[j], bt_ = btv[j];
    float cs_l = 0.f, con_l = 0.f;

    int rstride = gridDim.x * 4;
    for (int r = blockIdx.x * 4 + wid; r < n; r += rstride){
        int e0 = roff[r], e1 = roff[r + 1];
        float as_ = 0.f, at_ = 0.f;
        int e = e0 + slot;
        for (; e + 4 < e1; e += 8){
            uint2 c0 = csr[e];
            uint2 c1 = csr[e + 4];
            unsigned v0 = GSp[(size_t)c0.x * 16 + j];
            unsigned v1 = GSp[(size_t)c1.x * 16 + j];
            float w0 = __uint_as_float(c0.y), w1 = __uint_as_float(c1.y);
            as_ = fmaf(w0, bflo(v0), as_); at_ = fmaf(w0, bfhi(v0), at_);
            as_ = fmaf(w1, bflo(v1), as_); at_ = fmaf(w1, bfhi(v1), at_);
        }
        if (e < e1){
            uint2 c = csr[e];
            float w = __uint_as_float(c.y);
            unsigned v = GSp[(size_t)c.x * 16 + j];
            as_ = fmaf(w, bflo(v), as_);
            at_ = fmaf(w, bfhi(v), at_);
        }
        as_ += __shfl_xor(as_, 16); as_ += __shfl_xor(as_, 32);
        at_ += __shfl_xor(at_, 16); at_ += __shfl_xor(at_, 32);
        float xs = selu1(as_ + bs_);
        float xt = selu1(at_ + bt_);
        float ms = xs, mt = xt;
        #pragma unroll
        for (int off = 8; off >= 1; off >>= 1){
            ms = fmaxf(ms, __shfl_xor(ms, off));
            mt = fmaxf(mt, __shfl_xor(mt, off));
        }
        float es = expf(xs - ms), et = expf(xt - mt);
        float ss = es, st = et;
        #pragma unroll
        for (int off = 8; off >= 1; off >>= 1){
            ss += __shfl_xor(ss, off);
            st += __shfl_xor(st, off);
        }
        float a = es / ss, b = et / st;
        // pack assignments as bf16: dword d holds k=2d (lo), k=2d+1 (hi)
        int d = lane & 7;
        float alo = __shfl(a, 2 * d);
        float ahi = __shfl(a, 2 * d + 1);
        if (lane < 8)
            asgh[(size_t)r * 8 + d] = (unsigned)f2bf(alo) | ((unsigned)f2bf(ahi) << 16);
        cs_l += a;
        float dot = a * b, na = a * a, nb = b * b;
        #pragma unroll
        for (int off = 8; off >= 1; off >>= 1){
            dot += __shfl_xor(dot, off);
            na  += __shfl_xor(na, off);
            nb  += __shfl_xor(nb, off);
        }
        if (j == 0){
            na = fmaxf(sqrtf(na), 1e-12f);
            nb = fmaxf(sqrtf(nb), 1e-12f);
            con_l += 2.f - 2.f * dot / (na * nb);
        }
    }

    // slots hold exact duplicates -> combine then scale by 1/4
    cs_l  += __shfl_xor(cs_l, 16);  cs_l  += __shfl_xor(cs_l, 32);  cs_l  *= 0.25f;
    con_l += __shfl_xor(con_l, 16); con_l += __shfl_xor(con_l, 32); con_l *= 0.25f;

    __shared__ float part[4][17];
    if (lane < 16) part[wid][lane] = cs_l;
    if (lane == 0) part[wid][16]   = con_l;
    __syncthreads();
    if (tid < 16){
        float s = part[0][tid] + part[1][tid] + part[2][tid] + part[3][tid];
        atomicAdd(&red[(16 + tid) * RSTRIDE], s);
    } else if (tid == 16){
        float s = part[0][16] + part[1][16] + part[2][16] + part[3][16];
        atomicAdd(&red[32 * RSTRIDE], s);
    }
}

// ---------------- per-edge: trace + nl[k], bf16 assignment table, 2-edge unroll ------
__global__ __launch_bounds__(256) void edge_trace_kernel(const int* __restrict__ src,
        const int* __restrict__ dst, const unsigned* __restrict__ asgh,
        float* __restrict__ red, int E){
    int tid    = blockIdx.x * blockDim.x + threadIdx.x;
    int stride = gridDim.x * blockDim.x;
    float dot = 0.f;
    float nl[16] = {};

    #define EDGE(IA, IB) do{                                                     \
        const uint4* pa_ = reinterpret_cast<const uint4*>(asgh + (size_t)(IA) * 8); \
        const uint4* pb_ = reinterpret_cast<const uint4*>(asgh + (size_t)(IB) * 8); \
        uint4 a0_ = pa_[0], a1_ = pa_[1];                                         \
        uint4 b0_ = pb_[0], b1_ = pb_[1];                                         \
        unsigned aa_[8] = {a0_.x,a0_.y,a0_.z,a0_.w,a1_.x,a1_.y,a1_.z,a1_.w};      \
        unsigned bb_[8] = {b0_.x,b0_.y,b0_.z,b0_.w,b1_.x,b1_.y,b1_.z,b1_.w};      \
        _Pragma("unroll")                                                         \
        for (int q_ = 0; q_ < 8; ++q_){                                           \
            float bl_ = bflo(bb_[q_]), bh_ = bfhi(bb_[q_]);                       \
            dot = fmaf(bflo(aa_[q_]), bl_, dot);                                  \
            dot = fmaf(bfhi(aa_[q_]), bh_, dot);                                  \
            nl[2*q_]   += bl_;                                                    \
            nl[2*q_+1] += bh_;                                                    \
        } }while(0)

    int i = tid;
    for (; i + stride < E; i += 2 * stride){
        int s0 = src[i], d0 = dst[i];
        int s1 = src[i + stride], d1 = dst[i + stride];
        EDGE(s0, d0);
        EDGE(s1, d1);
    }
    if (i < E){
        int s0 = src[i], d0 = dst[i];
        EDGE(s0, d0);
    }
    #undef EDGE

    #pragma unroll
    for (int off = 1; off < 64; off <<= 1){
        dot += __shfl_xor(dot, off);
        #pragma unroll
        for (int k = 0; k < 16; ++k) nl[k] += __shfl_xor(nl[k], off);
    }
    __shared__ float part[4][17];
    int wid = threadIdx.x >> 6, lane = threadIdx.x & 63;
    if (lane == 0){
        #pragma unroll
        for (int k = 0; k < 16; ++k) part[wid][k] = nl[k];
        part[wid][16] = dot;
    }
    __syncthreads();
    int t = threadIdx.x;
    if (t < 16){
        float s = part[0][t] + part[1][t] + part[2][t] + part[3][t];
        atomicAdd(&red[t * RSTRIDE], s);
    } else if (t == 16){
        float s = part[0][16] + part[1][16] + part[2][16] + part[3][16];
        atomicAdd(&red[33 * RSTRIDE], s);
    }
}

// ---------------- finalize ----------------
__global__ void finalize_kernel(const float* __restrict__ red, float* __restrict__ out,
                                int n, int E){
    float trace = red[33 * RSTRIDE];
    float nl2 = 0.f, cs2 = 0.f;
    #pragma unroll
    for (int k = 0; k < 16; ++k){
        nl2 = fmaf(red[k * RSTRIDE],        red[k * RSTRIDE],        nl2);
        cs2 = fmaf(red[(16 + k) * RSTRIDE], red[(16 + k) * RSTRIDE], cs2);
    }
    float twoE = 2.f * (float)E;
    float spectral = -(trace - nl2 / twoE) / twoE;
    float cluster  = sqrtf(cs2) / (float)n * 4.f - 1.f;
    float con      = red[32 * RSTRIDE] / (float)n;
    out[0] = spectral + cluster + con;
}

extern "C" void kernel_launch(void* const* d_in, const int* in_sizes, int n_in,
                              void* d_out, int out_size, void* d_ws, size_t ws_size,
                              hipStream_t stream){
    const int*   esrc = (const int*)d_in[0];
    const int*   edst = (const int*)d_in[1];
    const float* ew   = (const float*)d_in[2];
    const float* feat = (const float*)d_in[3];
    const float* faug = (const float*)d_in[4];
    const float* W1   = (const float*)d_in[5];
    const float* b1   = (const float*)d_in[6];
    const float* Wsm  = (const float*)d_in[7];
    const float* bsv  = (const float*)d_in[8];
    const float* Wtm  = (const float*)d_in[9];
    const float* btv  = (const float*)d_in[10];
    int E = in_sizes[0];
    int N = in_sizes[3] / Fdim;

    char* ws = (char*)d_ws;
    size_t off = 0;
    auto alloc = [&](size_t bytes) -> char* {
        char* p = ws + off;
        off = (off + bytes + 255) & ~(size_t)255;
        return p;
    };
    int nbuck = (N + 255) >> 8;
    unsigned char* XWp = (unsigned char*)alloc((size_t)N * 512);  // fp8 [N][512B]
    ushort*   Gs    = (ushort*)alloc((size_t)N * Hdim * 2);
    ushort*   Gt    = (ushort*)alloc((size_t)N * Hdim * 2);
    unsigned* GSp   = (unsigned*)alloc((size_t)N * Kc * 4);
    unsigned* ASGH  = (unsigned*)alloc((size_t)N * 8 * 4);   // bf16-packed [N][16]
    ushort*   WT    = (ushort*)alloc((size_t)256 * 256 * 2);
    ushort*   WsT   = (ushort*)alloc((size_t)16 * 256 * 2);
    ushort*   WtT   = (ushort*)alloc((size_t)16 * 256 * 2);
    int*      ROFF  = (int*)alloc((size_t)(N + 1) * 4);
    int*      BCNT  = (int*)alloc((size_t)nbuck * 32 * 4);
    int*      BSRC  = (int*)alloc((size_t)nbuck * BCAP * 4);
    uint2*    BDW   = (uint2*)alloc((size_t)nbuck * BCAP * 8);
    uint2*    CSR8  = (uint2*)alloc((size_t)E * 8);
    float*    RED   = (float*)alloc((size_t)NRED * RSTRIDE * 4);

    prep_kernel<<<258, 256, 0, stream>>>(W1, WT, Wsm, Wtm, WsT, WtT, RED, BCNT, nbuck);

    int nrt = (N + 127) / 128;
    int mega_blocks = 256 + 2 * nrt * 2;
    mega_kernel<<<mega_blocks, 256, 0, stream>>>(esrc, edst, ew, BCNT, BSRC, BDW,
                                                 E, nbuck, feat, faug, WT, XWp,
                                                 N, nrt);

    csr_build_kernel<<<nbuck, 256, 0, stream>>>(BCNT, BSRC, BDW, ROFF, CSR8, N, nbuck);

    spmm_h2_kernel<<<(N + 3) / 4, 256, 0, stream>>>(XWp, ROFF, CSR8, b1, Gs, Gt, N);

    int nw = (N + 15) / 16;
    gemm_k2_kernel<<<(nw + 3) / 4, 256, 0, stream>>>(Gs, Gt, WsT, WtT, GSp, N);

    spmm_k2_kernel<<<1024, 256, 0, stream>>>(GSp, ROFF, CSR8, bsv, btv,
                                             ASGH, RED, N);

    edge_trace_kernel<<<256, 256, 0, stream>>>(esrc, edst, ASGH, RED, E);
    finalize_kernel<<<1, 1, 0, stream>>>(RED, (float*)d_out, N, E);
}